// Round 18
// baseline (388.527 us; speedup 1.0000x reference)
//
#include <hip/hip_runtime.h>

// ---------------------------------------------------------------------------
// B=16, L=1024, D=256, H=4 (DH=64), DFF=2048, C=3. Output: 17 elems.
// Dtype-adaptive (f32 or bf16 inputs; mode self-detected per block from W1's
// first 32KB — L2-hot, 0 hits for bf16, ~64 for f32, threshold 8).
// Wq/bq pre-scaled by 0.125*log2e so attention softmax is bare exp2.
// r18: mega-prep (transpose+ingest+embed, one launch); k_gemm64n BK=128
// quad-buffers (half the barriers, grid-capped occupancy unchanged).
// 13 launches. Attention at structural floor (~51.5us).
// ---------------------------------------------------------------------------

typedef unsigned short u16;
typedef u16    u16x4  __attribute__((ext_vector_type(4)));
typedef u16    u16x8  __attribute__((ext_vector_type(8)));
typedef __bf16 bf16x8 __attribute__((ext_vector_type(8)));
typedef float  f32x4  __attribute__((ext_vector_type(4)));

__device__ __forceinline__ float bf2f(u16 u) {
    union { unsigned int i; float f; } v; v.i = ((unsigned int)u) << 16; return v.f;
}
__device__ __forceinline__ u16 f2bf(float f) {
    union { float f; unsigned int i; } v; v.f = f;
    unsigned int r = (v.i + 0x7FFFu + ((v.i >> 16) & 1u)) >> 16;
    return (u16)r;
}
__device__ __forceinline__ u16 f2bf_fast(float f) {
    union { __bf16 h; u16 u; } v; v.h = (__bf16)f; return v.u;
}
__device__ __forceinline__ void gll16(const u16* g, u16* l) {
    __builtin_amdgcn_global_load_lds((__attribute__((address_space(1))) void*)(u16*)g,
                                     (__attribute__((address_space(3))) void*)l, 16, 0, 0);
}
// per-block self-detection: scan W1 raw first 16384 u16 (32KB, L2-hot).
// bf16 weights -> 0 NaN patterns; f32 lower-halves -> ~64. threshold 8.
__device__ __forceinline__ int detect_mode_block(const u16* __restrict__ w1raw) {
    __shared__ int bs[4];
    __shared__ int ms;
    int tid = threadIdx.x, nt = blockDim.x;
    if (tid < 4) bs[tid] = 0;
    __syncthreads();
    int bad = 0;
    for (int k = tid; k < 16384; k += nt) {
        unsigned v = w1raw[k] & 0x7FFFu;
        if (v >= 0x7F80u) bad++;
    }
    for (int off = 32; off >= 1; off >>= 1) bad += __shfl_xor(bad, off);
    if ((tid & 63) == 0) bs[tid >> 6] = bad;
    __syncthreads();
    if (tid == 0) ms = (bs[0] + bs[1] + bs[2] + bs[3]) > 8;
    __syncthreads();
    return ms;
}

__global__ void k_sentinel_f32(float* __restrict__ out, int code) {
    int t = threadIdx.x;
    if (t < 17) out[t] = (float)code;
}

// ---------------- mega-prep: transposes + small ingest + embed -------------
struct PrepTab {
    const void* src[7];
    u16*        dst[7];
    int         K[7], N[7];
    float       scale[7];
    int         tstart[8];     // transpose tiles; ingest=[tstart[7],+17); embed after
    const void* isrc[17];
    unsigned    idstoff[17];
    int         in[17];
    float       iscale[17];
    u16*        ing;
    const int*  si;
    const int*  ci;
    const void* se;
    const void* ce;
    u16*        X;
    const u16*  w1raw;
};
__global__ __launch_bounds__(256) void k_prep(PrepTab tt) {
    int m = detect_mode_block(tt.w1raw);
    int bx = blockIdx.x;
    int ibase = tt.tstart[7];
    if (bx >= ibase + 17) {                   // ---- embed blocks ----
        int eb = bx - (ibase + 17);
        int t = eb * 256 + threadIdx.x;
        int row = t >> 5, seg = (t & 31) * 8;
        int s = tt.si[row], c = tt.ci[row];
        u16x8 o;
        if (m) {
            const float* sp = (const float*)tt.se + s * 256 + seg;
            const float* cp = (const float*)tt.ce + c * 256 + seg;
#pragma unroll
            for (int e = 0; e < 8; ++e) o[e] = f2bf(sp[e] + cp[e]);
        } else {
            u16x8 a = *(const u16x8*)((const u16*)tt.se + s * 256 + seg);
            u16x8 b = *(const u16x8*)((const u16*)tt.ce + c * 256 + seg);
#pragma unroll
            for (int e = 0; e < 8; ++e) o[e] = f2bf(bf2f(a[e]) + bf2f(b[e]));
        }
        *(u16x8*)&tt.X[(size_t)row * 256 + seg] = o;
        return;
    }
    if (bx >= ibase) {                        // ---- small-tensor ingest ----
        int t = bx - ibase;
        int n = tt.in[t];
        float sc = tt.iscale[t];
        u16* dst = tt.ing + tt.idstoff[t];
        for (int i = threadIdx.x; i < n; i += 256) {
            float v = m ? ((const float*)tt.isrc[t])[i] : bf2f(((const u16*)tt.isrc[t])[i]);
            dst[i] = f2bf(v * sc);
        }
        return;
    }
    // ---- transpose tiles (fused convert) ----
    __shared__ u16 tile[32][33];
    int wgt = 0;
#pragma unroll
    for (int i = 1; i < 7; ++i) if (bx >= tt.tstart[i]) wgt = i;
    int local = bx - tt.tstart[wgt];
    int K = tt.K[wgt], N = tt.N[wgt];
    float sc = tt.scale[wgt];
    int ntx = N >> 5;
    int txt = local % ntx, tyt = local / ntx;
    const void* W = tt.src[wgt];
    u16* Wt = tt.dst[wgt];
    int tx = threadIdx.x & 31, ty = threadIdx.x >> 5;
    int n = txt * 32 + tx;
    for (int i = ty; i < 32; i += 8) {
        size_t idx = (size_t)(tyt * 32 + i) * N + n;
        float v = m ? ((const float*)W)[idx] : bf2f(((const u16*)W)[idx]);
        tile[i][tx] = f2bf(v * sc);
    }
    __syncthreads();
    int k2 = tyt * 32 + tx;
    for (int i = ty; i < 32; i += 8) {
        int n2 = txt * 32 + i;
        Wt[(size_t)n2 * K + k2] = tile[tx][i];
    }
}

// ---------------- MFMA GEMM 128x128, gll16, XCD-banded (FFN1) --------------
__global__ __launch_bounds__(256) void k_gemm_bt(const u16* __restrict__ A,
                                                 const u16* __restrict__ Bt,
                                                 const u16* __restrict__ bias,
                                                 u16* __restrict__ C,
                                                 int N, int K, int relu, int gx) {
    __shared__ u16 As[128][32];
    __shared__ u16 Bs[128][32];
    const int tid = threadIdx.x;
    const int xcd = blockIdx.x & 7, j = blockIdx.x >> 3;
    const int m0 = (xcd * 16 + j / gx) * 128, n0 = (j % gx) * 128;
    const int lane = tid & 63, wid = tid >> 6;
    const int wm = (wid & 1) * 64, wn = (wid >> 1) * 64;
    const int m16 = lane & 15, quad = lane >> 4;
    f32x4 acc[4][4] = {};
    const int arow = tid >> 2;
    const int ac8  = (tid & 3) * 8;
    const u16* Ap0 = A  + (size_t)(m0 + arow) * K + ac8;
    const u16* Ap1 = A  + (size_t)(m0 + 64 + arow) * K + ac8;
    const u16* Bp0 = Bt + (size_t)(n0 + arow) * K + ac8;
    const u16* Bp1 = Bt + (size_t)(n0 + 64 + arow) * K + ac8;
    u16* lA0 = &As[arow][ac8];
    u16* lA1 = &As[64 + arow][ac8];
    u16* lB0 = &Bs[arow][ac8];
    u16* lB1 = &Bs[64 + arow][ac8];

    for (int k0 = 0; k0 < K; k0 += 32) {
        __syncthreads();
        gll16(Ap0 + k0, lA0);
        gll16(Ap1 + k0, lA1);
        gll16(Bp0 + k0, lB0);
        gll16(Bp1 + k0, lB1);
        __syncthreads();
        bf16x8 af[4], bfv[4];
#pragma unroll
        for (int i = 0; i < 4; ++i)
            af[i] = *(const bf16x8*)&As[wm + i * 16 + m16][quad * 8];
#pragma unroll
        for (int j2 = 0; j2 < 4; ++j2)
            bfv[j2] = *(const bf16x8*)&Bs[wn + j2 * 16 + m16][quad * 8];
#pragma unroll
        for (int i = 0; i < 4; ++i)
#pragma unroll
            for (int j2 = 0; j2 < 4; ++j2)
                acc[i][j2] = __builtin_amdgcn_mfma_f32_16x16x32_bf16(
                    af[i], bfv[j2], acc[i][j2], 0, 0, 0);
    }

#pragma unroll
    for (int i = 0; i < 4; ++i) {
        int row = m0 + wm + i * 16 + quad * 4;
#pragma unroll
        for (int j2 = 0; j2 < 4; ++j2) {
            int col = n0 + wn + j2 * 16 + m16;
            float bv = bf2f(bias[col]);
#pragma unroll
            for (int r = 0; r < 4; ++r) {
                float v = acc[i][j2][r] + bv;
                if (relu) v = fmaxf(v, 0.f);
                C[(size_t)(row + r) * N + col] = f2bf_fast(v);
            }
        }
    }
}

// ---------------- MFMA GEMM 64x128, BK=64 (QKV; vt epilogue) ---------------
__global__ __launch_bounds__(256) void k_gemm64(const u16* __restrict__ A,
                                                const u16* __restrict__ Bt,
                                                const u16* __restrict__ bias,
                                                u16* __restrict__ C,
                                                int N, int K, int relu,
                                                int gx, int mtpx,
                                                u16* __restrict__ vt) {
    __shared__ u16 As0[64][32], As1[64][32];
    __shared__ u16 Bs0[128][32], Bs1[128][32];
    const int tid = threadIdx.x;
    const int xcd = blockIdx.x & 7, j = blockIdx.x >> 3;
    const int m0 = (xcd * mtpx + j / gx) * 64, n0 = (j % gx) * 128;
    const int vmode = (vt != nullptr) && (n0 >= 512);
    const int lane = tid & 63, wid = tid >> 6;
    const int wm = (wid & 1) * 32, wn = (wid >> 1) * 64;
    const int m16 = lane & 15, quad = lane >> 4;
    f32x4 acc[2][4] = {};
    const int arow = tid >> 2;
    const int ac8  = (tid & 3) * 8;
    const u16* Ap  = A  + (size_t)(m0 + arow) * K + ac8;
    const u16* Bp0 = Bt + (size_t)(n0 + arow) * K + ac8;
    const u16* Bp1 = Bt + (size_t)(n0 + 64 + arow) * K + ac8;
    u16* lA0  = &As0[arow][ac8];
    u16* lA1  = &As1[arow][ac8];
    u16* lB00 = &Bs0[arow][ac8];
    u16* lB01 = &Bs0[64 + arow][ac8];
    u16* lB10 = &Bs1[arow][ac8];
    u16* lB11 = &Bs1[64 + arow][ac8];

    for (int k0 = 0; k0 < K; k0 += 64) {
        __syncthreads();
        gll16(Ap + k0,        lA0);
        gll16(Ap + k0 + 32,   lA1);
        gll16(Bp0 + k0,       lB00);
        gll16(Bp0 + k0 + 32,  lB10);
        gll16(Bp1 + k0,       lB01);
        gll16(Bp1 + k0 + 32,  lB11);
        __syncthreads();
#pragma unroll
        for (int ks = 0; ks < 2; ++ks) {
            bf16x8 af[2], bfv[4];
#pragma unroll
            for (int i = 0; i < 2; ++i)
                af[i] = ks == 0 ? *(const bf16x8*)&As0[wm + i * 16 + m16][quad * 8]
                                : *(const bf16x8*)&As1[wm + i * 16 + m16][quad * 8];
#pragma unroll
            for (int j2 = 0; j2 < 4; ++j2)
                bfv[j2] = ks == 0 ? *(const bf16x8*)&Bs0[wn + j2 * 16 + m16][quad * 8]
                                  : *(const bf16x8*)&Bs1[wn + j2 * 16 + m16][quad * 8];
#pragma unroll
            for (int i = 0; i < 2; ++i)
#pragma unroll
                for (int j2 = 0; j2 < 4; ++j2)
                    acc[i][j2] = __builtin_amdgcn_mfma_f32_16x16x32_bf16(
                        af[i], bfv[j2], acc[i][j2], 0, 0, 0);
        }
    }

#pragma unroll
    for (int i = 0; i < 2; ++i) {
        int row = m0 + wm + i * 16 + quad * 4;
#pragma unroll
        for (int j2 = 0; j2 < 4; ++j2) {
            int col = n0 + wn + j2 * 16 + m16;
            float bv = bf2f(bias[col]);
            if (vmode) {
                int ch = col - 512;
                u16x4 o;
#pragma unroll
                for (int r = 0; r < 4; ++r) o[r] = f2bf_fast(acc[i][j2][r] + bv);
                size_t vb = ((size_t)((row >> 10) * 4 + (ch >> 6)) * 64 + (ch & 63)) * 1024
                          + (row & 1023);
                *(u16x4*)&vt[vb] = o;
            } else {
#pragma unroll
                for (int r = 0; r < 4; ++r) {
                    float v = acc[i][j2][r] + bv;
                    if (relu) v = fmaxf(v, 0.f);
                    C[(size_t)(row + r) * N + col] = f2bf_fast(v);
                }
            }
        }
    }
}

// ---------------- MFMA GEMM 64x64, BK=128 quad-buffers (N=256 GEMMs) -------
// gnx=4 -> 1024 blocks (grid-capped 4/CU); LDS 32KB (cap 5/CU > grid cap).
__global__ __launch_bounds__(256) void k_gemm64n(const u16* __restrict__ A,
                                                 const u16* __restrict__ Bt,
                                                 const u16* __restrict__ bias,
                                                 u16* __restrict__ C,
                                                 int N, int K, int relu,
                                                 int gnx, int mtpx,
                                                 const float* __restrict__ gate) {
    __shared__ u16 As[4][64][32];
    __shared__ u16 Bs[4][64][32];
    const int tid = threadIdx.x;
    const int xcd = blockIdx.x & 7, j = blockIdx.x >> 3;
    const int m0 = (xcd * mtpx + j / gnx) * 64, n0 = (j % gnx) * 64;
    if (gate && gate[m0] == 0.f) return;
    const int lane = tid & 63, w = tid >> 6;
    const int m16 = lane & 15, quad = lane >> 4;
    f32x4 acc[4] = {};
    const int arow = tid >> 2;
    const int ac8  = (tid & 3) * 8;
    const u16* Ap = A  + (size_t)(m0 + arow) * K + ac8;
    const u16* Bp = Bt + (size_t)(n0 + arow) * K + ac8;
    u16* lA[4]; u16* lB[4];
#pragma unroll
    for (int q = 0; q < 4; ++q) { lA[q] = &As[q][arow][ac8]; lB[q] = &Bs[q][arow][ac8]; }

    for (int k0 = 0; k0 < K; k0 += 128) {
        __syncthreads();
#pragma unroll
        for (int q = 0; q < 4; ++q) {
            gll16(Ap + k0 + q * 32, lA[q]);
            gll16(Bp + k0 + q * 32, lB[q]);
        }
        __syncthreads();
#pragma unroll
        for (int ks = 0; ks < 4; ++ks) {
            bf16x8 af = *(const bf16x8*)&As[ks][w * 16 + m16][quad * 8];
#pragma unroll
            for (int nt = 0; nt < 4; ++nt) {
                bf16x8 bfv = *(const bf16x8*)&Bs[ks][nt * 16 + m16][quad * 8];
                acc[nt] = __builtin_amdgcn_mfma_f32_16x16x32_bf16(af, bfv, acc[nt], 0, 0, 0);
            }
        }
    }

#pragma unroll
    for (int nt = 0; nt < 4; ++nt) {
        int col = n0 + nt * 16 + m16;
        float bv = bf2f(bias[col]);
        int row = m0 + w * 16 + quad * 4;
#pragma unroll
        for (int r = 0; r < 4; ++r) {
            float v = acc[nt][r] + bv;
            if (relu) v = fmaxf(v, 0.f);
            C[(size_t)(row + r) * N + col] = f2bf_fast(v);
        }
    }
}

// ---------------------------------------------------------------------------
// MFMA flash attention (structural floor): r13 structure + l-via-MFMA-ones.
// ---------------------------------------------------------------------------
__global__ __launch_bounds__(256) void k_attn_mfma(const u16* __restrict__ QKV,
                                                   const u16* __restrict__ VT,
                                                   u16* __restrict__ CTX) {
    __shared__ u16 Ks[64][72];
    __shared__ u16 Vts[64][72];
    __shared__ u16 Ps[4][16][72];
    const int tid = threadIdx.x, lane = tid & 63, w = tid >> 6;
    const int quad = lane >> 4, c = lane & 15;
    const int blk = blockIdx.x;
    const int xcd = blk & 7, local = blk >> 3;
    const int bh = xcd * 8 + (local >> 4);
    const int qt = local & 15;
    const int b = bh >> 2, h = bh & 3;
    const int qrow0 = b * 1024 + qt * 64;

    const u16* qptr = QKV + (size_t)(qrow0 + w * 16 + c) * 768 + h * 64;
    bf16x8 aq0 = *(const bf16x8*)(qptr + quad * 8);
    bf16x8 aq1 = *(const bf16x8*)(qptr + 32 + quad * 8);

    bf16x8 ones;
    {
        union { u16 u; __bf16 h; } v; v.u = 0x3F80;
#pragma unroll
        for (int e = 0; e < 8; ++e) ones[e] = v.h;
    }

    f32x4 acc_o[4] = {};
    f32x4 acc_l = {};

    const u16* kbase  = QKV + (size_t)(b * 1024) * 768 + 256 + h * 64;
    const u16* vtbase = VT + (size_t)(bh * 64) * 1024;
    const int skk = tid >> 3, sc8 = (tid & 7) * 8;

    for (int t = 0; t < 16; ++t) {
        __syncthreads();
#pragma unroll
        for (int it = 0; it < 2; ++it) {
            int rr = skk + 32 * it;
            *(u16x8*)&Ks[rr][sc8]  = *(const u16x8*)(kbase + (size_t)(t * 64 + rr) * 768 + sc8);
            *(u16x8*)&Vts[rr][sc8] = *(const u16x8*)(vtbase + (size_t)rr * 1024 + t * 64 + sc8);
        }
        __syncthreads();

        f32x4 s[4];
#pragma unroll
        for (int nt = 0; nt < 4; ++nt) {
            f32x4 z = {};
            bf16x8 bk0 = *(const bf16x8*)&Ks[nt * 16 + c][quad * 8];
            bf16x8 bk1 = *(const bf16x8*)&Ks[nt * 16 + c][32 + quad * 8];
            z = __builtin_amdgcn_mfma_f32_16x16x32_bf16(aq0, bk0, z, 0, 0, 0);
            s[nt] = __builtin_amdgcn_mfma_f32_16x16x32_bf16(aq1, bk1, z, 0, 0, 0);
        }

#pragma unroll
        for (int nt = 0; nt < 4; ++nt)
#pragma unroll
            for (int r = 0; r < 4; ++r)
                Ps[w][quad * 4 + r][nt * 16 + c] = f2bf_fast(exp2f(fminf(s[nt][r], 80.f)));

#pragma unroll
        for (int ks = 0; ks < 2; ++ks) {
            bf16x8 ap = *(const bf16x8*)&Ps[w][c][ks * 32 + quad * 8];
            acc_l = __builtin_amdgcn_mfma_f32_16x16x32_bf16(ap, ones, acc_l, 0, 0, 0);
#pragma unroll
            for (int nt = 0; nt < 4; ++nt) {
                bf16x8 bv = *(const bf16x8*)&Vts[nt * 16 + c][ks * 32 + quad * 8];
                acc_o[nt] = __builtin_amdgcn_mfma_f32_16x16x32_bf16(ap, bv, acc_o[nt], 0, 0, 0);
            }
        }
    }

#pragma unroll
    for (int nt = 0; nt < 4; ++nt) {
        int col = h * 64 + nt * 16 + c;
#pragma unroll
        for (int r = 0; r < 4; ++r) {
            int row = qrow0 + w * 16 + quad * 4 + r;
            CTX[(size_t)row * 256 + col] = f2bf_fast(acc_o[nt][r] / acc_l[r]);
        }
    }
}

// ---------------- LayerNorm (wave per row) — LN1 only ----------------
__global__ __launch_bounds__(256) void k_ln(const u16* __restrict__ A,
                                            const u16* __restrict__ R,
                                            const u16* __restrict__ g,
                                            const u16* __restrict__ be,
                                            u16* __restrict__ out) {
    int w = threadIdx.x >> 6, lane = threadIdx.x & 63;
    int row = blockIdx.x * 4 + w;
    size_t base = (size_t)row * 256 + lane * 4;
    u16x4 a4 = *(const u16x4*)&A[base];
    u16x4 r4 = *(const u16x4*)&R[base];
    float v[4];
    float s = 0.f, sq = 0.f;
#pragma unroll
    for (int j = 0; j < 4; ++j) {
        v[j] = bf2f(a4[j]) + bf2f(r4[j]);
        s += v[j]; sq += v[j] * v[j];
    }
    for (int off = 32; off >= 1; off >>= 1) { s += __shfl_xor(s, off); sq += __shfl_xor(sq, off); }
    float mean = s * (1.f / 256.f);
    float var  = sq * (1.f / 256.f) - mean * mean;
    float rs   = rsqrtf(var + 1e-5f);
    u16x4 o;
#pragma unroll
    for (int j = 0; j < 4; ++j) {
        int d = lane * 4 + j;
        o[j] = f2bf((v[j] - mean) * rs * bf2f(g[d]) + bf2f(be[d]));
    }
    *(u16x4*)&out[base] = o;
}

// ---------------- LN2 + logits / KL / flags fused (KL partials) ------------
__global__ __launch_bounds__(256) void k_logits(const u16* __restrict__ FFO,
                                                const u16* __restrict__ Y1,
                                                const u16* __restrict__ g2,
                                                const u16* __restrict__ be2,
                                                const u16* __restrict__ Wl,
                                                const u16* __restrict__ bl,
                                                u16* __restrict__ Y2,
                                                float* __restrict__ klpart,
                                                int* __restrict__ flags) {
    const int tid = threadIdx.x, lane = tid & 63, w = tid >> 6;
    float wv[4][3], gv[4], bev[4];
#pragma unroll
    for (int j = 0; j < 4; ++j) {
        int d = lane * 4 + j;
        gv[j]  = bf2f(g2[d]);
        bev[j] = bf2f(be2[d]);
#pragma unroll
        for (int c = 0; c < 3; ++c) wv[j][c] = bf2f(Wl[d * 3 + c]);
    }
    const float b0 = bf2f(bl[0]), b1 = bf2f(bl[1]), b2 = bf2f(bl[2]);
    float klsum = 0.f;
    const int row0 = blockIdx.x * 16 + w * 4;
    for (int i = 0; i < 4; ++i) {
        int row = row0 + i;
        size_t base = (size_t)row * 256 + lane * 4;
        u16x4 f4 = *(const u16x4*)&FFO[base];
        u16x4 y4 = *(const u16x4*)&Y1[base];
        float v[4];
        float s = 0.f, sq = 0.f;
#pragma unroll
        for (int j = 0; j < 4; ++j) {
            v[j] = bf2f(f4[j]) + bf2f(y4[j]);
            s += v[j]; sq += v[j] * v[j];
        }
        for (int off = 32; off >= 1; off >>= 1) { s += __shfl_xor(s, off); sq += __shfl_xor(sq, off); }
        float mean = s * (1.f / 256.f);
        float var  = sq * (1.f / 256.f) - mean * mean;
        float rs   = rsqrtf(var + 1e-5f);
        u16x4 o;
        float a0 = 0.f, a1 = 0.f, a2 = 0.f;
#pragma unroll
        for (int j = 0; j < 4; ++j) {
            float yn = (v[j] - mean) * rs * gv[j] + bev[j];
            o[j] = f2bf(yn);
            float y = bf2f(o[j]);
            a0 += y * wv[j][0]; a1 += y * wv[j][1]; a2 += y * wv[j][2];
        }
        *(u16x4*)&Y2[base] = o;
        for (int off = 32; off >= 1; off >>= 1) {
            a0 += __shfl_xor(a0, off); a1 += __shfl_xor(a1, off); a2 += __shfl_xor(a2, off);
        }
        if (lane == 0) {
            float l0 = a0 + b0, l1 = a1 + b1, l2 = a2 + b2;
            float mx = fmaxf(l0, fmaxf(l1, l2));
            float lse = mx + __logf(__expf(l0 - mx) + __expf(l1 - mx) + __expf(l2 - mx));
            klsum += lse - (l0 + l1 + l2) * (1.f / 3.f) - 1.0986122886681098f;
            int am = 0; float bv = l0;
            if (l1 > bv) { bv = l1; am = 1; }
            if (l2 > bv) { am = 2; }
            int l = row & 1023;
            flags[row] = (am == 0 && l != 0) ? 1 : 0;
        }
    }
    __shared__ float kls[4];
    if (lane == 0) kls[w] = klsum;
    __syncthreads();
    if (tid == 0) klpart[blockIdx.x] = kls[0] + kls[1] + kls[2] + kls[3];
}

// per-batch exclusive scan
__global__ void k_scan(const int* __restrict__ flags, int* __restrict__ seg) {
    __shared__ int wsum[16];
    int b = blockIdx.x, t = threadIdx.x;
    int lane = t & 63, w = t >> 6;
    int f = flags[b * 1024 + t];
    int x = f;
#pragma unroll
    for (int off = 1; off < 64; off <<= 1) {
        int v = __shfl_up(x, off);
        if (lane >= off) x += v;
    }
    if (lane == 63) wsum[w] = x;
    __syncthreads();
    if (w == 0) {
        int s = (lane < 16) ? wsum[lane] : 0;
#pragma unroll
        for (int off = 1; off < 16; off <<= 1) {
            int v = __shfl_up(s, off);
            if (lane >= off) s += v;
        }
        if (lane < 16) wsum[lane] = s;
    }
    __syncthreads();
    int prefix = (w > 0) ? wsum[w - 1] : 0;
    seg[b * 1024 + t] = prefix + x - f;
}

// ---------------- segmean ----------------
__global__ __launch_bounds__(64) void k_segmean(const u16* __restrict__ Y,
                                                const int* __restrict__ seg,
                                                u16* __restrict__ means,
                                                float* __restrict__ cnt) {
    int g = blockIdx.x, lane = threadIdx.x;
    int b = g >> 10, s = g & 1023;
    const int* sb = seg + b * 1024;
    int target = s + (lane & 1);
    int lo = 0, hi = 1024;
    while (lo < hi) {
        int mid = (lo + hi) >> 1;
        if (sb[mid] < target) lo = mid + 1; else hi = mid;
    }
    int start = __shfl(lo, 0);
    int end   = __shfl(lo, 1);
    int n = end - start;
    if (lane == 0) cnt[g] = (float)n;
    if (n <= 0) return;
    f32x4 acc = {};
    for (int row = start; row < end; ++row) {
        u16x4 y4 = *(const u16x4*)&Y[(size_t)(b * 1024 + row) * 256 + lane * 4];
        acc[0] += bf2f(y4[0]); acc[1] += bf2f(y4[1]);
        acc[2] += bf2f(y4[2]); acc[3] += bf2f(y4[3]);
    }
    float inv = 1.f / (float)n;
    u16x4 o;
#pragma unroll
    for (int j = 0; j < 4; ++j) o[j] = f2bf(acc[j] * inv);
    *(u16x4*)&means[(size_t)g * 256 + lane * 4] = o;
}

// ---------------- predicate head: plain per-block partials ----------------
__global__ __launch_bounds__(256) void k_preds(const u16* __restrict__ T,
                                               const u16* __restrict__ Wp2,
                                               const u16* __restrict__ bp2,
                                               const u16* __restrict__ wc,
                                               const u16* __restrict__ bc,
                                               const float* __restrict__ cnt,
                                               float* __restrict__ predp) {
    const int tid = threadIdx.x, lane = tid & 63, w = tid >> 6;
    float lwp[4];
#pragma unroll
    for (int j = 0; j < 4; ++j) lwp[j] = bf2f(Wp2[lane * 4 + j]);
    const float fb = bf2f(bp2[0]), fw = bf2f(wc[0]), fc = bf2f(bc[0]);
    float csum = 0.f, vsum = 0.f;
    const int g0 = blockIdx.x * 16 + w * 4;
    if (cnt[g0] != 0.f) {
        for (int i = 0; i < 4; ++i) {
            int g = g0 + i;
            u16x4 t4 = *(const u16x4*)&T[(size_t)g * 256 + lane * 4];
            float a = 0.f;
#pragma unroll
            for (int j = 0; j < 4; ++j) a += bf2f(t4[j]) * lwp[j];
            for (int off = 32; off >= 1; off >>= 1) a += __shfl_xor(a, off);
            if (lane == 0 && cnt[g] > 0.f) {
                float pred = 1.f / (1.f + __expf(-(a + fb)));
                csum += pred * fw + fc;
                vsum += 1.f;
            }
        }
    }
    __shared__ float cs[4], vs[4];
    if (lane == 0) { cs[w] = csum; vs[w] = vsum; }
    __syncthreads();
    if (tid == 0) {
        predp[2 * blockIdx.x]     = cs[0] + cs[1] + cs[2] + cs[3];
        predp[2 * blockIdx.x + 1] = vs[0] + vs[1] + vs[2] + vs[3];
    }
}

// ---------------- finalize: sum KL + pred partials, store ----------------
__global__ void k_final(const float* __restrict__ predp, const float* __restrict__ klp,
                        const u16* __restrict__ w1raw, void* __restrict__ outv) {
    int mode = detect_mode_block(w1raw);
    int t = threadIdx.x;   // 64
    float k = 0.f;
    for (int i = t; i < 1024; i += 64) k += klp[i];
    for (int off = 32; off >= 1; off >>= 1) k += __shfl_xor(k, off);
    float ktot = __shfl(k, 0);
    int batch = t >> 2, ch = t & 3;
    float c = 0.f, v = 0.f;
    for (int i = 0; i < 16; ++i) {
        int blk = batch * 64 + ch * 16 + i;
        c += predp[2 * blk];
        v += predp[2 * blk + 1];
    }
    c += __shfl_xor(c, 1); c += __shfl_xor(c, 2);
    v += __shfl_xor(v, 1); v += __shfl_xor(v, 2);
    if ((t & 3) == 0) {
        float d = v, nm = c;
        if (!(d > 0.f)) d = 1.f;
        if (isnan(nm) || isinf(nm)) nm = 0.f;
        float val = 1.f / (1.f + __expf(-nm / d));
        if (mode) ((float*)outv)[batch] = val;
        else      ((u16*)outv)[batch]   = f2bf(val);
    }
    if (t == 1) {
        float val = ktot * (1.f / 16.f);
        if (isnan(val) || isinf(val)) val = 0.f;
        if (mode) ((float*)outv)[16] = val;
        else      ((u16*)outv)[16]   = f2bf(val);
    }
}

// ---------------------------------------------------------------------------
extern "C" void kernel_launch(void* const* d_in, const int* in_sizes, int n_in,
                              void* d_out, int out_size, void* d_ws, size_t ws_size,
                              hipStream_t stream) {
    const int* shape_idxs = (const int*)d_in[0];
    const int* color_idxs = (const int*)d_in[1];
    char* ws = (char*)d_ws;
    const size_t MB = 1024 * 1024;

    if (ws_size < 90 * MB) {
        int wsMB = (int)(ws_size >> 20); if (wsMB > 250) wsMB = 250;
        k_sentinel_f32<<<1, 32, 0, stream>>>((float*)d_out, 200 + wsMB);
        return;
    }

    // ---- arena ----
    u16*   X     = (u16*)(ws);
    u16*   QKVb  = (u16*)(ws + 8 * MB);
    u16*   VT    = (u16*)(ws + 32 * MB);
    u16*   CTX   = (u16*)(ws + 40 * MB);
    u16*   CTXP  = (u16*)(ws + 48 * MB);
    u16*   Y1    = (u16*)(ws + 64 * MB);
    u16*   Hb    = (u16*)(ws);
    u16*   FFO   = (u16*)(ws + 72 * MB);
    u16*   Y2    = (u16*)(ws);
    u16*   MEANS = (u16*)(ws + 24 * MB);
    u16*   TB    = (u16*)(ws + 32 * MB);
    int*   FLAGS = (int*)(ws + 80 * MB);
    int*   SEG   = (int*)(ws + 80 * MB + 65536);
    float* CNT   = (float*)(ws + 80 * MB + 131072);
    float* KLP   = (float*)(ws + 80 * MB + 262144);
    float* PREDP = (float*)(ws + 80 * MB + 327680);
    u16*   W3T   = (u16*)(ws + 81 * MB);
    u16*   WoT   = (u16*)(ws + 81 * MB + 786432);
    u16*   Wp1T  = (u16*)(ws + 81 * MB + 917504);
    u16*   W1T   = (u16*)(ws + 82 * MB);
    u16*   W2T   = (u16*)(ws + 83 * MB);
    u16*   ING   = (u16*)(ws + 85 * MB);

    const float QSCALE = 0.125f * 1.44269504f;
    const u16* w1raw = (const u16*)d_in[14];

    // prep table: 7 transposes + 17 ingests + 2048 embed blocks
    PrepTab tt;
    const void* tsrc[7] = {d_in[4], d_in[6], d_in[8], d_in[10], d_in[22], d_in[14], d_in[16]};
    u16* tdst[7] = {W3T, W3T + 256 * 256, W3T + 512 * 256, WoT, Wp1T, W1T, W2T};
    int tK[7] = {256, 256, 256, 256, 256, 256, 2048};
    int tN[7] = {256, 256, 256, 256, 256, 2048, 256};
    int ts = 0;
    for (int i = 0; i < 7; ++i) {
        tt.src[i] = tsrc[i]; tt.dst[i] = tdst[i]; tt.K[i] = tK[i]; tt.N[i] = tN[i];
        tt.scale[i] = (i == 0) ? QSCALE : 1.0f;
        tt.tstart[i] = ts;
        ts += (tK[i] >> 5) * (tN[i] >> 5);
    }
    tt.tstart[7] = ts;

    static const int II[17]  = {5, 7, 9, 11, 12, 13, 15, 17, 18, 19, 20, 21, 23, 24, 25, 26, 27};
    static const int IN[17]  = {256, 256, 256, 256, 256, 256, 2048, 256, 256, 256, 768, 3, 256, 256, 1, 1, 1};
    unsigned off = 0;
    for (int i = 0; i < 17; ++i) {
        tt.isrc[i] = d_in[II[i]];
        tt.in[i] = IN[i];
        tt.iscale[i] = 1.0f;
        if (i == 0) { tt.idstoff[0] = off; off += 768; }
        else if (i == 1) tt.idstoff[1] = tt.idstoff[0] + 256;
        else if (i == 2) tt.idstoff[2] = tt.idstoff[0] + 512;
        else { tt.idstoff[i] = off; off += (unsigned)((IN[i] + 8) & ~7); }
    }
    tt.iscale[0] = QSCALE;   // bq
    tt.ing = ING;
    tt.si = shape_idxs; tt.ci = color_idxs;
    tt.se = d_in[2]; tt.ce = d_in[3];
    tt.X = X; tt.w1raw = w1raw;
    const u16* ib3  = ING + tt.idstoff[0];
    const u16* ibo  = ING + tt.idstoff[3];
    const u16* ig1  = ING + tt.idstoff[4];  const u16* ibe1 = ING + tt.idstoff[5];
    const u16* ibf1 = ING + tt.idstoff[6];  const u16* ibf2 = ING + tt.idstoff[7];
    const u16* ig2  = ING + tt.idstoff[8];  const u16* ibe2 = ING + tt.idstoff[9];
    const u16* iWl  = ING + tt.idstoff[10]; const u16* ibl  = ING + tt.idstoff[11];
    const u16* ibp1 = ING + tt.idstoff[12]; const u16* iWp2 = ING + tt.idstoff[13];
    const u16* ibp2 = ING + tt.idstoff[14]; const u16* iwc  = ING + tt.idstoff[15];
    const u16* ibc  = ING + tt.idstoff[16];

    // 1) mega-prep: transposes + ingest + embed, one launch (self-detect mode)
    k_prep<<<ts + 17 + 2048, 256, 0, stream>>>(tt);
    // 2) fused QKV projection; V columns written directly in VT layout
    k_gemm64<<<1536, 256, 0, stream>>>(X, W3T, ib3, QKVb, 768, 256, 0, 6, 32, VT);
    // 3) attention
    k_attn_mfma<<<1024, 256, 0, stream>>>(QKVb, VT, CTX);
    // 4) Wo (64x64 BK=128) + LN1
    k_gemm64n<<<1024, 256, 0, stream>>>(CTX, WoT, ibo, CTXP, 256, 256, 0, 4, 32, nullptr);
    k_ln<<<4096, 256, 0, stream>>>(CTXP, X, ig1, ibe1, Y1);
    // 5) FFN: FFN1 128-tile, FFN2 64x64 BK=128
    k_gemm_bt<<<16 * 128, 256, 0, stream>>>(Y1, W1T, ibf1, Hb, 2048, 256, 1, 16);
    k_gemm64n<<<1024, 256, 0, stream>>>(Hb, W2T, ibf2, FFO, 256, 2048, 0, 4, 32, nullptr);
    // 6) LN2 + logits / KL / flags (fused; writes Y2, KL partials)
    k_logits<<<1024, 256, 0, stream>>>(FFO, Y1, ig2, ibe2, iWl, ibl, Y2, KLP, FLAGS);
    // 7) per-batch exclusive scan
    k_scan<<<16, 1024, 0, stream>>>(FLAGS, SEG);
    // 8) segment means
    k_segmean<<<16384, 64, 0, stream>>>(Y2, SEG, MEANS, CNT);
    // 9) predicate net (gated, BK=128) -> plain partials
    k_gemm64n<<<1024, 256, 0, stream>>>(MEANS, Wp1T, ibp1, TB, 256, 256, 1, 4, 32, CNT);
    k_preds<<<1024, 256, 0, stream>>>(TB, iWp2, ibp2, iwc, ibc, CNT, PREDP);
    // 10) finalize + store (self-detect mode)
    k_final<<<1, 64, 0, stream>>>(PREDP, KLP, w1raw, d_out);
}

// Round 19
// 307.271 us; speedup vs baseline: 1.2644x; 1.2644x over previous
//
#include <hip/hip_runtime.h>

// ---------------------------------------------------------------------------
// B=16, L=1024, D=256, H=4 (DH=64), DFF=2048, C=3. Output: 17 elems.
// Dtype-adaptive (f32 or bf16 inputs; PARALLEL k_detect -> DETP partials;
// consumers sum 64 ints). Wq/bq pre-scaled by 0.125*log2e (softmax = exp2).
// r19: revert r18's self-detect (single-block scan = r9 trap, cost 72us in
// k_final); keep mega-prep (transpose+ingest+embed) and BK=128 gemm64n.
// 14 launches. Attention at structural floor (~51.5us).
// ---------------------------------------------------------------------------

typedef unsigned short u16;
typedef u16    u16x4  __attribute__((ext_vector_type(4)));
typedef u16    u16x8  __attribute__((ext_vector_type(8)));
typedef __bf16 bf16x8 __attribute__((ext_vector_type(8)));
typedef float  f32x4  __attribute__((ext_vector_type(4)));

__device__ __forceinline__ float bf2f(u16 u) {
    union { unsigned int i; float f; } v; v.i = ((unsigned int)u) << 16; return v.f;
}
__device__ __forceinline__ u16 f2bf(float f) {
    union { float f; unsigned int i; } v; v.f = f;
    unsigned int r = (v.i + 0x7FFFu + ((v.i >> 16) & 1u)) >> 16;
    return (u16)r;
}
__device__ __forceinline__ u16 f2bf_fast(float f) {
    union { __bf16 h; u16 u; } v; v.h = (__bf16)f; return v.u;
}
__device__ __forceinline__ void gll16(const u16* g, u16* l) {
    __builtin_amdgcn_global_load_lds((__attribute__((address_space(1))) void*)(u16*)g,
                                     (__attribute__((address_space(3))) void*)l, 16, 0, 0);
}
// cheap mode read: sum 64 plain per-block detect partials (L2-hot ints)
__device__ __forceinline__ int get_mode(const int* __restrict__ detp) {
    int s = 0;
#pragma unroll 8
    for (int i = 0; i < 64; ++i) s += detp[i];
    return s > 16;
}

// ---------------- dtype detection: 64 parallel blocks, plain partials ------
__global__ __launch_bounds__(256) void k_detect(const u16* __restrict__ w1raw,
                                                int* __restrict__ detp) {
    int i = blockIdx.x * 256 + threadIdx.x;
    int bad = 0;
    for (int k = i; k < 65536; k += 64 * 256) {
        unsigned v = w1raw[k] & 0x7FFFu;
        if (v >= 0x7F80u) bad++;
    }
    for (int off = 32; off >= 1; off >>= 1) bad += __shfl_xor(bad, off);
    __shared__ int bs[4];
    if ((threadIdx.x & 63) == 0) bs[threadIdx.x >> 6] = bad;
    __syncthreads();
    if (threadIdx.x == 0) detp[blockIdx.x] = bs[0] + bs[1] + bs[2] + bs[3];
}

__global__ void k_sentinel_f32(float* __restrict__ out, int code) {
    int t = threadIdx.x;
    if (t < 17) out[t] = (float)code;
}

// ---------------- mega-prep: transposes + small ingest + embed -------------
struct PrepTab {
    const void* src[7];
    u16*        dst[7];
    int         K[7], N[7];
    float       scale[7];
    int         tstart[8];     // transpose tiles; ingest=[tstart[7],+17); embed after
    const void* isrc[17];
    unsigned    idstoff[17];
    int         in[17];
    float       iscale[17];
    u16*        ing;
    const int*  si;
    const int*  ci;
    const void* se;
    const void* ce;
    u16*        X;
};
__global__ __launch_bounds__(256) void k_prep(PrepTab tt, const int* __restrict__ detp) {
    int m = get_mode(detp);
    int bx = blockIdx.x;
    int ibase = tt.tstart[7];
    if (bx >= ibase + 17) {                   // ---- embed blocks ----
        int eb = bx - (ibase + 17);
        int t = eb * 256 + threadIdx.x;
        int row = t >> 5, seg = (t & 31) * 8;
        int s = tt.si[row], c = tt.ci[row];
        u16x8 o;
        if (m) {
            const float* sp = (const float*)tt.se + s * 256 + seg;
            const float* cp = (const float*)tt.ce + c * 256 + seg;
#pragma unroll
            for (int e = 0; e < 8; ++e) o[e] = f2bf(sp[e] + cp[e]);
        } else {
            u16x8 a = *(const u16x8*)((const u16*)tt.se + s * 256 + seg);
            u16x8 b = *(const u16x8*)((const u16*)tt.ce + c * 256 + seg);
#pragma unroll
            for (int e = 0; e < 8; ++e) o[e] = f2bf(bf2f(a[e]) + bf2f(b[e]));
        }
        *(u16x8*)&tt.X[(size_t)row * 256 + seg] = o;
        return;
    }
    if (bx >= ibase) {                        // ---- small-tensor ingest ----
        int t = bx - ibase;
        int n = tt.in[t];
        float sc = tt.iscale[t];
        u16* dst = tt.ing + tt.idstoff[t];
        for (int i = threadIdx.x; i < n; i += 256) {
            float v = m ? ((const float*)tt.isrc[t])[i] : bf2f(((const u16*)tt.isrc[t])[i]);
            dst[i] = f2bf(v * sc);
        }
        return;
    }
    // ---- transpose tiles (fused convert) ----
    __shared__ u16 tile[32][33];
    int wgt = 0;
#pragma unroll
    for (int i = 1; i < 7; ++i) if (bx >= tt.tstart[i]) wgt = i;
    int local = bx - tt.tstart[wgt];
    int K = tt.K[wgt], N = tt.N[wgt];
    float sc = tt.scale[wgt];
    int ntx = N >> 5;
    int txt = local % ntx, tyt = local / ntx;
    const void* W = tt.src[wgt];
    u16* Wt = tt.dst[wgt];
    int tx = threadIdx.x & 31, ty = threadIdx.x >> 5;
    int n = txt * 32 + tx;
    for (int i = ty; i < 32; i += 8) {
        size_t idx = (size_t)(tyt * 32 + i) * N + n;
        float v = m ? ((const float*)W)[idx] : bf2f(((const u16*)W)[idx]);
        tile[i][tx] = f2bf(v * sc);
    }
    __syncthreads();
    int k2 = tyt * 32 + tx;
    for (int i = ty; i < 32; i += 8) {
        int n2 = txt * 32 + i;
        Wt[(size_t)n2 * K + k2] = tile[tx][i];
    }
}

// ---------------- MFMA GEMM 128x128, gll16, XCD-banded (FFN1) --------------
__global__ __launch_bounds__(256) void k_gemm_bt(const u16* __restrict__ A,
                                                 const u16* __restrict__ Bt,
                                                 const u16* __restrict__ bias,
                                                 u16* __restrict__ C,
                                                 int N, int K, int relu, int gx) {
    __shared__ u16 As[128][32];
    __shared__ u16 Bs[128][32];
    const int tid = threadIdx.x;
    const int xcd = blockIdx.x & 7, j = blockIdx.x >> 3;
    const int m0 = (xcd * 16 + j / gx) * 128, n0 = (j % gx) * 128;
    const int lane = tid & 63, wid = tid >> 6;
    const int wm = (wid & 1) * 64, wn = (wid >> 1) * 64;
    const int m16 = lane & 15, quad = lane >> 4;
    f32x4 acc[4][4] = {};
    const int arow = tid >> 2;
    const int ac8  = (tid & 3) * 8;
    const u16* Ap0 = A  + (size_t)(m0 + arow) * K + ac8;
    const u16* Ap1 = A  + (size_t)(m0 + 64 + arow) * K + ac8;
    const u16* Bp0 = Bt + (size_t)(n0 + arow) * K + ac8;
    const u16* Bp1 = Bt + (size_t)(n0 + 64 + arow) * K + ac8;
    u16* lA0 = &As[arow][ac8];
    u16* lA1 = &As[64 + arow][ac8];
    u16* lB0 = &Bs[arow][ac8];
    u16* lB1 = &Bs[64 + arow][ac8];

    for (int k0 = 0; k0 < K; k0 += 32) {
        __syncthreads();
        gll16(Ap0 + k0, lA0);
        gll16(Ap1 + k0, lA1);
        gll16(Bp0 + k0, lB0);
        gll16(Bp1 + k0, lB1);
        __syncthreads();
        bf16x8 af[4], bfv[4];
#pragma unroll
        for (int i = 0; i < 4; ++i)
            af[i] = *(const bf16x8*)&As[wm + i * 16 + m16][quad * 8];
#pragma unroll
        for (int j2 = 0; j2 < 4; ++j2)
            bfv[j2] = *(const bf16x8*)&Bs[wn + j2 * 16 + m16][quad * 8];
#pragma unroll
        for (int i = 0; i < 4; ++i)
#pragma unroll
            for (int j2 = 0; j2 < 4; ++j2)
                acc[i][j2] = __builtin_amdgcn_mfma_f32_16x16x32_bf16(
                    af[i], bfv[j2], acc[i][j2], 0, 0, 0);
    }

#pragma unroll
    for (int i = 0; i < 4; ++i) {
        int row = m0 + wm + i * 16 + quad * 4;
#pragma unroll
        for (int j2 = 0; j2 < 4; ++j2) {
            int col = n0 + wn + j2 * 16 + m16;
            float bv = bf2f(bias[col]);
#pragma unroll
            for (int r = 0; r < 4; ++r) {
                float v = acc[i][j2][r] + bv;
                if (relu) v = fmaxf(v, 0.f);
                C[(size_t)(row + r) * N + col] = f2bf_fast(v);
            }
        }
    }
}

// ---------------- MFMA GEMM 64x128, BK=64 (QKV; vt epilogue) ---------------
__global__ __launch_bounds__(256) void k_gemm64(const u16* __restrict__ A,
                                                const u16* __restrict__ Bt,
                                                const u16* __restrict__ bias,
                                                u16* __restrict__ C,
                                                int N, int K, int relu,
                                                int gx, int mtpx,
                                                u16* __restrict__ vt) {
    __shared__ u16 As0[64][32], As1[64][32];
    __shared__ u16 Bs0[128][32], Bs1[128][32];
    const int tid = threadIdx.x;
    const int xcd = blockIdx.x & 7, j = blockIdx.x >> 3;
    const int m0 = (xcd * mtpx + j / gx) * 64, n0 = (j % gx) * 128;
    const int vmode = (vt != nullptr) && (n0 >= 512);
    const int lane = tid & 63, wid = tid >> 6;
    const int wm = (wid & 1) * 32, wn = (wid >> 1) * 64;
    const int m16 = lane & 15, quad = lane >> 4;
    f32x4 acc[2][4] = {};
    const int arow = tid >> 2;
    const int ac8  = (tid & 3) * 8;
    const u16* Ap  = A  + (size_t)(m0 + arow) * K + ac8;
    const u16* Bp0 = Bt + (size_t)(n0 + arow) * K + ac8;
    const u16* Bp1 = Bt + (size_t)(n0 + 64 + arow) * K + ac8;
    u16* lA0  = &As0[arow][ac8];
    u16* lA1  = &As1[arow][ac8];
    u16* lB00 = &Bs0[arow][ac8];
    u16* lB01 = &Bs0[64 + arow][ac8];
    u16* lB10 = &Bs1[arow][ac8];
    u16* lB11 = &Bs1[64 + arow][ac8];

    for (int k0 = 0; k0 < K; k0 += 64) {
        __syncthreads();
        gll16(Ap + k0,        lA0);
        gll16(Ap + k0 + 32,   lA1);
        gll16(Bp0 + k0,       lB00);
        gll16(Bp0 + k0 + 32,  lB10);
        gll16(Bp1 + k0,       lB01);
        gll16(Bp1 + k0 + 32,  lB11);
        __syncthreads();
#pragma unroll
        for (int ks = 0; ks < 2; ++ks) {
            bf16x8 af[2], bfv[4];
#pragma unroll
            for (int i = 0; i < 2; ++i)
                af[i] = ks == 0 ? *(const bf16x8*)&As0[wm + i * 16 + m16][quad * 8]
                                : *(const bf16x8*)&As1[wm + i * 16 + m16][quad * 8];
#pragma unroll
            for (int j2 = 0; j2 < 4; ++j2)
                bfv[j2] = ks == 0 ? *(const bf16x8*)&Bs0[wn + j2 * 16 + m16][quad * 8]
                                  : *(const bf16x8*)&Bs1[wn + j2 * 16 + m16][quad * 8];
#pragma unroll
            for (int i = 0; i < 2; ++i)
#pragma unroll
                for (int j2 = 0; j2 < 4; ++j2)
                    acc[i][j2] = __builtin_amdgcn_mfma_f32_16x16x32_bf16(
                        af[i], bfv[j2], acc[i][j2], 0, 0, 0);
        }
    }

#pragma unroll
    for (int i = 0; i < 2; ++i) {
        int row = m0 + wm + i * 16 + quad * 4;
#pragma unroll
        for (int j2 = 0; j2 < 4; ++j2) {
            int col = n0 + wn + j2 * 16 + m16;
            float bv = bf2f(bias[col]);
            if (vmode) {
                int ch = col - 512;
                u16x4 o;
#pragma unroll
                for (int r = 0; r < 4; ++r) o[r] = f2bf_fast(acc[i][j2][r] + bv);
                size_t vb = ((size_t)((row >> 10) * 4 + (ch >> 6)) * 64 + (ch & 63)) * 1024
                          + (row & 1023);
                *(u16x4*)&vt[vb] = o;
            } else {
#pragma unroll
                for (int r = 0; r < 4; ++r) {
                    float v = acc[i][j2][r] + bv;
                    if (relu) v = fmaxf(v, 0.f);
                    C[(size_t)(row + r) * N + col] = f2bf_fast(v);
                }
            }
        }
    }
}

// ---------------- MFMA GEMM 64x64, BK=128 quad-buffers (N=256 GEMMs) -------
__global__ __launch_bounds__(256) void k_gemm64n(const u16* __restrict__ A,
                                                 const u16* __restrict__ Bt,
                                                 const u16* __restrict__ bias,
                                                 u16* __restrict__ C,
                                                 int N, int K, int relu,
                                                 int gnx, int mtpx,
                                                 const float* __restrict__ gate) {
    __shared__ u16 As[4][64][32];
    __shared__ u16 Bs[4][64][32];
    const int tid = threadIdx.x;
    const int xcd = blockIdx.x & 7, j = blockIdx.x >> 3;
    const int m0 = (xcd * mtpx + j / gnx) * 64, n0 = (j % gnx) * 64;
    if (gate && gate[m0] == 0.f) return;
    const int lane = tid & 63, w = tid >> 6;
    const int m16 = lane & 15, quad = lane >> 4;
    f32x4 acc[4] = {};
    const int arow = tid >> 2;
    const int ac8  = (tid & 3) * 8;
    const u16* Ap = A  + (size_t)(m0 + arow) * K + ac8;
    const u16* Bp = Bt + (size_t)(n0 + arow) * K + ac8;
    u16* lA[4]; u16* lB[4];
#pragma unroll
    for (int q = 0; q < 4; ++q) { lA[q] = &As[q][arow][ac8]; lB[q] = &Bs[q][arow][ac8]; }

    for (int k0 = 0; k0 < K; k0 += 128) {
        __syncthreads();
#pragma unroll
        for (int q = 0; q < 4; ++q) {
            gll16(Ap + k0 + q * 32, lA[q]);
            gll16(Bp + k0 + q * 32, lB[q]);
        }
        __syncthreads();
#pragma unroll
        for (int ks = 0; ks < 4; ++ks) {
            bf16x8 af = *(const bf16x8*)&As[ks][w * 16 + m16][quad * 8];
#pragma unroll
            for (int nt = 0; nt < 4; ++nt) {
                bf16x8 bfv = *(const bf16x8*)&Bs[ks][nt * 16 + m16][quad * 8];
                acc[nt] = __builtin_amdgcn_mfma_f32_16x16x32_bf16(af, bfv, acc[nt], 0, 0, 0);
            }
        }
    }

#pragma unroll
    for (int nt = 0; nt < 4; ++nt) {
        int col = n0 + nt * 16 + m16;
        float bv = bf2f(bias[col]);
        int row = m0 + w * 16 + quad * 4;
#pragma unroll
        for (int r = 0; r < 4; ++r) {
            float v = acc[nt][r] + bv;
            if (relu) v = fmaxf(v, 0.f);
            C[(size_t)(row + r) * N + col] = f2bf_fast(v);
        }
    }
}

// ---------------------------------------------------------------------------
// MFMA flash attention (structural floor): r13 structure + l-via-MFMA-ones.
// ---------------------------------------------------------------------------
__global__ __launch_bounds__(256) void k_attn_mfma(const u16* __restrict__ QKV,
                                                   const u16* __restrict__ VT,
                                                   u16* __restrict__ CTX) {
    __shared__ u16 Ks[64][72];
    __shared__ u16 Vts[64][72];
    __shared__ u16 Ps[4][16][72];
    const int tid = threadIdx.x, lane = tid & 63, w = tid >> 6;
    const int quad = lane >> 4, c = lane & 15;
    const int blk = blockIdx.x;
    const int xcd = blk & 7, local = blk >> 3;
    const int bh = xcd * 8 + (local >> 4);
    const int qt = local & 15;
    const int b = bh >> 2, h = bh & 3;
    const int qrow0 = b * 1024 + qt * 64;

    const u16* qptr = QKV + (size_t)(qrow0 + w * 16 + c) * 768 + h * 64;
    bf16x8 aq0 = *(const bf16x8*)(qptr + quad * 8);
    bf16x8 aq1 = *(const bf16x8*)(qptr + 32 + quad * 8);

    bf16x8 ones;
    {
        union { u16 u; __bf16 h; } v; v.u = 0x3F80;
#pragma unroll
        for (int e = 0; e < 8; ++e) ones[e] = v.h;
    }

    f32x4 acc_o[4] = {};
    f32x4 acc_l = {};

    const u16* kbase  = QKV + (size_t)(b * 1024) * 768 + 256 + h * 64;
    const u16* vtbase = VT + (size_t)(bh * 64) * 1024;
    const int skk = tid >> 3, sc8 = (tid & 7) * 8;

    for (int t = 0; t < 16; ++t) {
        __syncthreads();
#pragma unroll
        for (int it = 0; it < 2; ++it) {
            int rr = skk + 32 * it;
            *(u16x8*)&Ks[rr][sc8]  = *(const u16x8*)(kbase + (size_t)(t * 64 + rr) * 768 + sc8);
            *(u16x8*)&Vts[rr][sc8] = *(const u16x8*)(vtbase + (size_t)rr * 1024 + t * 64 + sc8);
        }
        __syncthreads();

        f32x4 s[4];
#pragma unroll
        for (int nt = 0; nt < 4; ++nt) {
            f32x4 z = {};
            bf16x8 bk0 = *(const bf16x8*)&Ks[nt * 16 + c][quad * 8];
            bf16x8 bk1 = *(const bf16x8*)&Ks[nt * 16 + c][32 + quad * 8];
            z = __builtin_amdgcn_mfma_f32_16x16x32_bf16(aq0, bk0, z, 0, 0, 0);
            s[nt] = __builtin_amdgcn_mfma_f32_16x16x32_bf16(aq1, bk1, z, 0, 0, 0);
        }

#pragma unroll
        for (int nt = 0; nt < 4; ++nt)
#pragma unroll
            for (int r = 0; r < 4; ++r)
                Ps[w][quad * 4 + r][nt * 16 + c] = f2bf_fast(exp2f(fminf(s[nt][r], 80.f)));

#pragma unroll
        for (int ks = 0; ks < 2; ++ks) {
            bf16x8 ap = *(const bf16x8*)&Ps[w][c][ks * 32 + quad * 8];
            acc_l = __builtin_amdgcn_mfma_f32_16x16x32_bf16(ap, ones, acc_l, 0, 0, 0);
#pragma unroll
            for (int nt = 0; nt < 4; ++nt) {
                bf16x8 bv = *(const bf16x8*)&Vts[nt * 16 + c][ks * 32 + quad * 8];
                acc_o[nt] = __builtin_amdgcn_mfma_f32_16x16x32_bf16(ap, bv, acc_o[nt], 0, 0, 0);
            }
        }
    }

#pragma unroll
    for (int nt = 0; nt < 4; ++nt) {
        int col = h * 64 + nt * 16 + c;
#pragma unroll
        for (int r = 0; r < 4; ++r) {
            int row = qrow0 + w * 16 + quad * 4 + r;
            CTX[(size_t)row * 256 + col] = f2bf_fast(acc_o[nt][r] / acc_l[r]);
        }
    }
}

// ---------------- LayerNorm (wave per row) — LN1 only ----------------
__global__ __launch_bounds__(256) void k_ln(const u16* __restrict__ A,
                                            const u16* __restrict__ R,
                                            const u16* __restrict__ g,
                                            const u16* __restrict__ be,
                                            u16* __restrict__ out) {
    int w = threadIdx.x >> 6, lane = threadIdx.x & 63;
    int row = blockIdx.x * 4 + w;
    size_t base = (size_t)row * 256 + lane * 4;
    u16x4 a4 = *(const u16x4*)&A[base];
    u16x4 r4 = *(const u16x4*)&R[base];
    float v[4];
    float s = 0.f, sq = 0.f;
#pragma unroll
    for (int j = 0; j < 4; ++j) {
        v[j] = bf2f(a4[j]) + bf2f(r4[j]);
        s += v[j]; sq += v[j] * v[j];
    }
    for (int off = 32; off >= 1; off >>= 1) { s += __shfl_xor(s, off); sq += __shfl_xor(sq, off); }
    float mean = s * (1.f / 256.f);
    float var  = sq * (1.f / 256.f) - mean * mean;
    float rs   = rsqrtf(var + 1e-5f);
    u16x4 o;
#pragma unroll
    for (int j = 0; j < 4; ++j) {
        int d = lane * 4 + j;
        o[j] = f2bf((v[j] - mean) * rs * bf2f(g[d]) + bf2f(be[d]));
    }
    *(u16x4*)&out[base] = o;
}

// ---------------- LN2 + logits / KL / flags fused (KL partials) ------------
__global__ __launch_bounds__(256) void k_logits(const u16* __restrict__ FFO,
                                                const u16* __restrict__ Y1,
                                                const u16* __restrict__ g2,
                                                const u16* __restrict__ be2,
                                                const u16* __restrict__ Wl,
                                                const u16* __restrict__ bl,
                                                u16* __restrict__ Y2,
                                                float* __restrict__ klpart,
                                                int* __restrict__ flags) {
    const int tid = threadIdx.x, lane = tid & 63, w = tid >> 6;
    float wv[4][3], gv[4], bev[4];
#pragma unroll
    for (int j = 0; j < 4; ++j) {
        int d = lane * 4 + j;
        gv[j]  = bf2f(g2[d]);
        bev[j] = bf2f(be2[d]);
#pragma unroll
        for (int c = 0; c < 3; ++c) wv[j][c] = bf2f(Wl[d * 3 + c]);
    }
    const float b0 = bf2f(bl[0]), b1 = bf2f(bl[1]), b2 = bf2f(bl[2]);
    float klsum = 0.f;
    const int row0 = blockIdx.x * 16 + w * 4;
    for (int i = 0; i < 4; ++i) {
        int row = row0 + i;
        size_t base = (size_t)row * 256 + lane * 4;
        u16x4 f4 = *(const u16x4*)&FFO[base];
        u16x4 y4 = *(const u16x4*)&Y1[base];
        float v[4];
        float s = 0.f, sq = 0.f;
#pragma unroll
        for (int j = 0; j < 4; ++j) {
            v[j] = bf2f(f4[j]) + bf2f(y4[j]);
            s += v[j]; sq += v[j] * v[j];
        }
        for (int off = 32; off >= 1; off >>= 1) { s += __shfl_xor(s, off); sq += __shfl_xor(sq, off); }
        float mean = s * (1.f / 256.f);
        float var  = sq * (1.f / 256.f) - mean * mean;
        float rs   = rsqrtf(var + 1e-5f);
        u16x4 o;
        float a0 = 0.f, a1 = 0.f, a2 = 0.f;
#pragma unroll
        for (int j = 0; j < 4; ++j) {
            float yn = (v[j] - mean) * rs * gv[j] + bev[j];
            o[j] = f2bf(yn);
            float y = bf2f(o[j]);
            a0 += y * wv[j][0]; a1 += y * wv[j][1]; a2 += y * wv[j][2];
        }
        *(u16x4*)&Y2[base] = o;
        for (int off = 32; off >= 1; off >>= 1) {
            a0 += __shfl_xor(a0, off); a1 += __shfl_xor(a1, off); a2 += __shfl_xor(a2, off);
        }
        if (lane == 0) {
            float l0 = a0 + b0, l1 = a1 + b1, l2 = a2 + b2;
            float mx = fmaxf(l0, fmaxf(l1, l2));
            float lse = mx + __logf(__expf(l0 - mx) + __expf(l1 - mx) + __expf(l2 - mx));
            klsum += lse - (l0 + l1 + l2) * (1.f / 3.f) - 1.0986122886681098f;
            int am = 0; float bv = l0;
            if (l1 > bv) { bv = l1; am = 1; }
            if (l2 > bv) { am = 2; }
            int l = row & 1023;
            flags[row] = (am == 0 && l != 0) ? 1 : 0;
        }
    }
    __shared__ float kls[4];
    if (lane == 0) kls[w] = klsum;
    __syncthreads();
    if (tid == 0) klpart[blockIdx.x] = kls[0] + kls[1] + kls[2] + kls[3];
}

// per-batch exclusive scan
__global__ void k_scan(const int* __restrict__ flags, int* __restrict__ seg) {
    __shared__ int wsum[16];
    int b = blockIdx.x, t = threadIdx.x;
    int lane = t & 63, w = t >> 6;
    int f = flags[b * 1024 + t];
    int x = f;
#pragma unroll
    for (int off = 1; off < 64; off <<= 1) {
        int v = __shfl_up(x, off);
        if (lane >= off) x += v;
    }
    if (lane == 63) wsum[w] = x;
    __syncthreads();
    if (w == 0) {
        int s = (lane < 16) ? wsum[lane] : 0;
#pragma unroll
        for (int off = 1; off < 16; off <<= 1) {
            int v = __shfl_up(s, off);
            if (lane >= off) s += v;
        }
        if (lane < 16) wsum[lane] = s;
    }
    __syncthreads();
    int prefix = (w > 0) ? wsum[w - 1] : 0;
    seg[b * 1024 + t] = prefix + x - f;
}

// ---------------- segmean ----------------
__global__ __launch_bounds__(64) void k_segmean(const u16* __restrict__ Y,
                                                const int* __restrict__ seg,
                                                u16* __restrict__ means,
                                                float* __restrict__ cnt) {
    int g = blockIdx.x, lane = threadIdx.x;
    int b = g >> 10, s = g & 1023;
    const int* sb = seg + b * 1024;
    int target = s + (lane & 1);
    int lo = 0, hi = 1024;
    while (lo < hi) {
        int mid = (lo + hi) >> 1;
        if (sb[mid] < target) lo = mid + 1; else hi = mid;
    }
    int start = __shfl(lo, 0);
    int end   = __shfl(lo, 1);
    int n = end - start;
    if (lane == 0) cnt[g] = (float)n;
    if (n <= 0) return;
    f32x4 acc = {};
    for (int row = start; row < end; ++row) {
        u16x4 y4 = *(const u16x4*)&Y[(size_t)(b * 1024 + row) * 256 + lane * 4];
        acc[0] += bf2f(y4[0]); acc[1] += bf2f(y4[1]);
        acc[2] += bf2f(y4[2]); acc[3] += bf2f(y4[3]);
    }
    float inv = 1.f / (float)n;
    u16x4 o;
#pragma unroll
    for (int j = 0; j < 4; ++j) o[j] = f2bf(acc[j] * inv);
    *(u16x4*)&means[(size_t)g * 256 + lane * 4] = o;
}

// ---------------- predicate head: plain per-block partials ----------------
__global__ __launch_bounds__(256) void k_preds(const u16* __restrict__ T,
                                               const u16* __restrict__ Wp2,
                                               const u16* __restrict__ bp2,
                                               const u16* __restrict__ wc,
                                               const u16* __restrict__ bc,
                                               const float* __restrict__ cnt,
                                               float* __restrict__ predp) {
    const int tid = threadIdx.x, lane = tid & 63, w = tid >> 6;
    float lwp[4];
#pragma unroll
    for (int j = 0; j < 4; ++j) lwp[j] = bf2f(Wp2[lane * 4 + j]);
    const float fb = bf2f(bp2[0]), fw = bf2f(wc[0]), fc = bf2f(bc[0]);
    float csum = 0.f, vsum = 0.f;
    const int g0 = blockIdx.x * 16 + w * 4;
    if (cnt[g0] != 0.f) {
        for (int i = 0; i < 4; ++i) {
            int g = g0 + i;
            u16x4 t4 = *(const u16x4*)&T[(size_t)g * 256 + lane * 4];
            float a = 0.f;
#pragma unroll
            for (int j = 0; j < 4; ++j) a += bf2f(t4[j]) * lwp[j];
            for (int off = 32; off >= 1; off >>= 1) a += __shfl_xor(a, off);
            if (lane == 0 && cnt[g] > 0.f) {
                float pred = 1.f / (1.f + __expf(-(a + fb)));
                csum += pred * fw + fc;
                vsum += 1.f;
            }
        }
    }
    __shared__ float cs[4], vs[4];
    if (lane == 0) { cs[w] = csum; vs[w] = vsum; }
    __syncthreads();
    if (tid == 0) {
        predp[2 * blockIdx.x]     = cs[0] + cs[1] + cs[2] + cs[3];
        predp[2 * blockIdx.x + 1] = vs[0] + vs[1] + vs[2] + vs[3];
    }
}

// ---------------- finalize: sum KL + pred partials, store ----------------
__global__ void k_final(const float* __restrict__ predp, const float* __restrict__ klp,
                        const int* __restrict__ detp, void* __restrict__ outv) {
    int mode = get_mode(detp);
    int t = threadIdx.x;   // 64
    float k = 0.f;
    for (int i = t; i < 1024; i += 64) k += klp[i];
    for (int off = 32; off >= 1; off >>= 1) k += __shfl_xor(k, off);
    float ktot = __shfl(k, 0);
    int batch = t >> 2, ch = t & 3;
    float c = 0.f, v = 0.f;
    for (int i = 0; i < 16; ++i) {
        int blk = batch * 64 + ch * 16 + i;
        c += predp[2 * blk];
        v += predp[2 * blk + 1];
    }
    c += __shfl_xor(c, 1); c += __shfl_xor(c, 2);
    v += __shfl_xor(v, 1); v += __shfl_xor(v, 2);
    if ((t & 3) == 0) {
        float d = v, nm = c;
        if (!(d > 0.f)) d = 1.f;
        if (isnan(nm) || isinf(nm)) nm = 0.f;
        float val = 1.f / (1.f + __expf(-nm / d));
        if (mode) ((float*)outv)[batch] = val;
        else      ((u16*)outv)[batch]   = f2bf(val);
    }
    if (t == 1) {
        float val = ktot * (1.f / 16.f);
        if (isnan(val) || isinf(val)) val = 0.f;
        if (mode) ((float*)outv)[16] = val;
        else      ((u16*)outv)[16]   = f2bf(val);
    }
}

// ---------------------------------------------------------------------------
extern "C" void kernel_launch(void* const* d_in, const int* in_sizes, int n_in,
                              void* d_out, int out_size, void* d_ws, size_t ws_size,
                              hipStream_t stream) {
    const int* shape_idxs = (const int*)d_in[0];
    const int* color_idxs = (const int*)d_in[1];
    char* ws = (char*)d_ws;
    const size_t MB = 1024 * 1024;

    if (ws_size < 90 * MB) {
        int wsMB = (int)(ws_size >> 20); if (wsMB > 250) wsMB = 250;
        k_sentinel_f32<<<1, 32, 0, stream>>>((float*)d_out, 200 + wsMB);
        return;
    }

    // ---- arena ----
    u16*   X     = (u16*)(ws);
    u16*   QKVb  = (u16*)(ws + 8 * MB);
    u16*   VT    = (u16*)(ws + 32 * MB);
    u16*   CTX   = (u16*)(ws + 40 * MB);
    u16*   CTXP  = (u16*)(ws + 48 * MB);
    u16*   Y1    = (u16*)(ws + 64 * MB);
    u16*   Hb    = (u16*)(ws);
    u16*   FFO   = (u16*)(ws + 72 * MB);
    u16*   Y2    = (u16*)(ws);
    u16*   MEANS = (u16*)(ws + 24 * MB);
    u16*   TB    = (u16*)(ws + 32 * MB);
    int*   FLAGS = (int*)(ws + 80 * MB);
    int*   SEG   = (int*)(ws + 80 * MB + 65536);
    float* CNT   = (float*)(ws + 80 * MB + 131072);
    float* KLP   = (float*)(ws + 80 * MB + 262144);
    float* PREDP = (float*)(ws + 80 * MB + 327680);
    u16*   W3T   = (u16*)(ws + 81 * MB);
    u16*   WoT   = (u16*)(ws + 81 * MB + 786432);
    u16*   Wp1T  = (u16*)(ws + 81 * MB + 917504);
    u16*   W1T   = (u16*)(ws + 82 * MB);
    u16*   W2T   = (u16*)(ws + 83 * MB);
    int*   DETP  = (int*)(ws + 84 * MB);
    u16*   ING   = (u16*)(ws + 85 * MB);

    const float QSCALE = 0.125f * 1.44269504f;
    const u16* w1raw = (const u16*)d_in[14];

    // prep table: 7 transposes + 17 ingests + 2048 embed blocks
    PrepTab tt;
    const void* tsrc[7] = {d_in[4], d_in[6], d_in[8], d_in[10], d_in[22], d_in[14], d_in[16]};
    u16* tdst[7] = {W3T, W3T + 256 * 256, W3T + 512 * 256, WoT, Wp1T, W1T, W2T};
    int tK[7] = {256, 256, 256, 256, 256, 256, 2048};
    int tN[7] = {256, 256, 256, 256, 256, 2048, 256};
    int ts = 0;
    for (int i = 0; i < 7; ++i) {
        tt.src[i] = tsrc[i]; tt.dst[i] = tdst[i]; tt.K[i] = tK[i]; tt.N[i] = tN[i];
        tt.scale[i] = (i == 0) ? QSCALE : 1.0f;
        tt.tstart[i] = ts;
        ts += (tK[i] >> 5) * (tN[i] >> 5);
    }
    tt.tstart[7] = ts;

    static const int II[17]  = {5, 7, 9, 11, 12, 13, 15, 17, 18, 19, 20, 21, 23, 24, 25, 26, 27};
    static const int IN[17]  = {256, 256, 256, 256, 256, 256, 2048, 256, 256, 256, 768, 3, 256, 256, 1, 1, 1};
    unsigned off = 0;
    for (int i = 0; i < 17; ++i) {
        tt.isrc[i] = d_in[II[i]];
        tt.in[i] = IN[i];
        tt.iscale[i] = 1.0f;
        if (i == 0) { tt.idstoff[0] = off; off += 768; }
        else if (i == 1) tt.idstoff[1] = tt.idstoff[0] + 256;
        else if (i == 2) tt.idstoff[2] = tt.idstoff[0] + 512;
        else { tt.idstoff[i] = off; off += (unsigned)((IN[i] + 8) & ~7); }
    }
    tt.iscale[0] = QSCALE;   // bq
    tt.ing = ING;
    tt.si = shape_idxs; tt.ci = color_idxs;
    tt.se = d_in[2]; tt.ce = d_in[3];
    tt.X = X;
    const u16* ib3  = ING + tt.idstoff[0];
    const u16* ibo  = ING + tt.idstoff[3];
    const u16* ig1  = ING + tt.idstoff[4];  const u16* ibe1 = ING + tt.idstoff[5];
    const u16* ibf1 = ING + tt.idstoff[6];  const u16* ibf2 = ING + tt.idstoff[7];
    const u16* ig2  = ING + tt.idstoff[8];  const u16* ibe2 = ING + tt.idstoff[9];
    const u16* iWl  = ING + tt.idstoff[10]; const u16* ibl  = ING + tt.idstoff[11];
    const u16* ibp1 = ING + tt.idstoff[12]; const u16* iWp2 = ING + tt.idstoff[13];
    const u16* ibp2 = ING + tt.idstoff[14]; const u16* iwc  = ING + tt.idstoff[15];
    const u16* ibc  = ING + tt.idstoff[16];

    // 0) parallel detect (64 blocks, plain partials)
    k_detect<<<64, 256, 0, stream>>>(w1raw, DETP);
    // 1) mega-prep: transposes + ingest + embed, one launch
    k_prep<<<ts + 17 + 2048, 256, 0, stream>>>(tt, DETP);
    // 2) fused QKV projection; V columns written directly in VT layout
    k_gemm64<<<1536, 256, 0, stream>>>(X, W3T, ib3, QKVb, 768, 256, 0, 6, 32, VT);
    // 3) attention
    k_attn_mfma<<<1024, 256, 0, stream>>>(QKVb, VT, CTX);
    // 4) Wo (64x64 BK=128) + LN1
    k_gemm64n<<<1024, 256, 0, stream>>>(CTX, WoT, ibo, CTXP, 256, 256, 0, 4, 32, nullptr);
    k_ln<<<4096, 256, 0, stream>>>(CTXP, X, ig1, ibe1, Y1);
    // 5) FFN: FFN1 128-tile, FFN2 64x64 BK=128
    k_gemm_bt<<<16 * 128, 256, 0, stream>>>(Y1, W1T, ibf1, Hb, 2048, 256, 1, 16);
    k_gemm64n<<<1024, 256, 0, stream>>>(Hb, W2T, ibf2, FFO, 256, 2048, 0, 4, 32, nullptr);
    // 6) LN2 + logits / KL / flags (fused; writes Y2, KL partials)
    k_logits<<<1024, 256, 0, stream>>>(FFO, Y1, ig2, ibe2, iWl, ibl, Y2, KLP, FLAGS);
    // 7) per-batch exclusive scan
    k_scan<<<16, 1024, 0, stream>>>(FLAGS, SEG);
    // 8) segment means
    k_segmean<<<16384, 64, 0, stream>>>(Y2, SEG, MEANS, CNT);
    // 9) predicate net (gated, BK=128) -> plain partials
    k_gemm64n<<<1024, 256, 0, stream>>>(MEANS, Wp1T, ibp1, TB, 256, 256, 1, 4, 32, CNT);
    k_preds<<<1024, 256, 0, stream>>>(TB, iWp2, ibp2, iwc, ibc, CNT, PREDP);
    // 10) finalize + store
    k_final<<<1, 64, 0, stream>>>(PREDP, KLP, DETP, d_out);
}

// Round 20
// 298.249 us; speedup vs baseline: 1.3027x; 1.0303x over previous
//
#include <hip/hip_runtime.h>

// ---------------------------------------------------------------------------
// B=16, L=1024, D=256, H=4 (DH=64), DFF=2048, C=3. Output: 17 elems.
// Dtype-adaptive (f32 or bf16 inputs; mode from DETP partial sums). Wq/bq
// pre-scaled by 0.125*log2e so attention softmax is bare exp2.
// FINAL (r17 configuration — measured best, 300.4us): k_gemm64n (64x64 BK=64,
// 4 blocks/CU) for the N=256 latency-bound GEMMs (Wo, FFN2, TB); ingest
// folded into the transpose mega-kernel; separate embed launch. 15 launches.
// Attention at its structural floor (~51.5us): r13 structure + l-via-MFMA.
// ---------------------------------------------------------------------------

typedef unsigned short u16;
typedef u16    u16x4  __attribute__((ext_vector_type(4)));
typedef u16    u16x8  __attribute__((ext_vector_type(8)));
typedef __bf16 bf16x8 __attribute__((ext_vector_type(8)));
typedef float  f32x4  __attribute__((ext_vector_type(4)));

__device__ __forceinline__ float bf2f(u16 u) {
    union { unsigned int i; float f; } v; v.i = ((unsigned int)u) << 16; return v.f;
}
__device__ __forceinline__ u16 f2bf(float f) {
    union { float f; unsigned int i; } v; v.f = f;
    unsigned int r = (v.i + 0x7FFFu + ((v.i >> 16) & 1u)) >> 16;
    return (u16)r;
}
__device__ __forceinline__ u16 f2bf_fast(float f) {
    union { __bf16 h; u16 u; } v; v.h = (__bf16)f; return v.u;
}
__device__ __forceinline__ void gll16(const u16* g, u16* l) {
    __builtin_amdgcn_global_load_lds((__attribute__((address_space(1))) void*)(u16*)g,
                                     (__attribute__((address_space(3))) void*)l, 16, 0, 0);
}
__device__ __forceinline__ int get_mode(const int* __restrict__ detp) {
    int s = 0;
#pragma unroll 8
    for (int i = 0; i < 64; ++i) s += detp[i];
    return s > 16;
}

// ---------------- dtype detection: plain per-block partials ----------------
__global__ __launch_bounds__(256) void k_detect(const u16* __restrict__ w1raw,
                                                int* __restrict__ detp) {
    int i = blockIdx.x * 256 + threadIdx.x;
    int bad = 0;
    for (int k = i; k < 65536; k += 64 * 256) {
        unsigned v = w1raw[k] & 0x7FFFu;
        if (v >= 0x7F80u) bad++;
    }
    for (int off = 32; off >= 1; off >>= 1) bad += __shfl_xor(bad, off);
    __shared__ int bs[4];
    if ((threadIdx.x & 63) == 0) bs[threadIdx.x >> 6] = bad;
    __syncthreads();
    if (threadIdx.x == 0) detp[blockIdx.x] = bs[0] + bs[1] + bs[2] + bs[3];
}
__global__ void k_sentinel_f32(float* __restrict__ out, int code) {
    int t = threadIdx.x;
    if (t < 17) out[t] = (float)code;
}

// ---------------- prep: transpose (fused convert) + small ingest -----------
struct PrepTab {
    const void* src[7];
    u16*        dst[7];
    int         K[7], N[7];
    float       scale[7];
    int         tstart[8];     // transpose tile ranges; ingest = [tstart[7], +17)
    const void* isrc[17];
    unsigned    idstoff[17];
    int         in[17];
    float       iscale[17];
    u16*        ing;
};
__global__ __launch_bounds__(256) void k_prep(PrepTab tt, const int* __restrict__ detp) {
    int m = get_mode(detp);
    int bx = blockIdx.x;
    if (bx >= tt.tstart[7]) {                 // ---- small-tensor ingest ----
        int t = bx - tt.tstart[7];
        int n = tt.in[t];
        float sc = tt.iscale[t];
        u16* dst = tt.ing + tt.idstoff[t];
        for (int i = threadIdx.x; i < n; i += 256) {
            float v = m ? ((const float*)tt.isrc[t])[i] : bf2f(((const u16*)tt.isrc[t])[i]);
            dst[i] = f2bf(v * sc);
        }
        return;
    }
    __shared__ u16 tile[32][33];
    int wgt = 0;
#pragma unroll
    for (int i = 1; i < 7; ++i) if (bx >= tt.tstart[i]) wgt = i;
    int local = bx - tt.tstart[wgt];
    int K = tt.K[wgt], N = tt.N[wgt];
    float sc = tt.scale[wgt];
    int ntx = N >> 5;
    int txt = local % ntx, tyt = local / ntx;
    const void* W = tt.src[wgt];
    u16* Wt = tt.dst[wgt];
    int tx = threadIdx.x & 31, ty = threadIdx.x >> 5;
    int n = txt * 32 + tx;
    for (int i = ty; i < 32; i += 8) {
        size_t idx = (size_t)(tyt * 32 + i) * N + n;
        float v = m ? ((const float*)W)[idx] : bf2f(((const u16*)W)[idx]);
        tile[i][tx] = f2bf(v * sc);
    }
    __syncthreads();
    int k2 = tyt * 32 + tx;
    for (int i = ty; i < 32; i += 8) {
        int n2 = txt * 32 + i;
        Wt[(size_t)n2 * K + k2] = tile[tx][i];
    }
}

// ---------------- embedding (adaptive raw reads) ----------------
__global__ __launch_bounds__(256) void k_embed(const int* __restrict__ si,
                                               const int* __restrict__ ci,
                                               const void* __restrict__ se,
                                               const void* __restrict__ ce,
                                               u16* __restrict__ X,
                                               const int* __restrict__ detp) {
    int m = get_mode(detp);
    int t = blockIdx.x * 256 + threadIdx.x;
    int row = t >> 5, seg = (t & 31) * 8;
    int s = si[row], c = ci[row];
    u16x8 o;
    if (m) {
        const float* sp = (const float*)se + s * 256 + seg;
        const float* cp = (const float*)ce + c * 256 + seg;
#pragma unroll
        for (int e = 0; e < 8; ++e) o[e] = f2bf(sp[e] + cp[e]);
    } else {
        u16x8 a = *(const u16x8*)((const u16*)se + s * 256 + seg);
        u16x8 b = *(const u16x8*)((const u16*)ce + c * 256 + seg);
#pragma unroll
        for (int e = 0; e < 8; ++e) o[e] = f2bf(bf2f(a[e]) + bf2f(b[e]));
    }
    *(u16x8*)&X[(size_t)row * 256 + seg] = o;
}

// ---------------- MFMA GEMM 128x128, gll16, XCD-banded (FFN1) --------------
__global__ __launch_bounds__(256) void k_gemm_bt(const u16* __restrict__ A,
                                                 const u16* __restrict__ Bt,
                                                 const u16* __restrict__ bias,
                                                 u16* __restrict__ C,
                                                 int N, int K, int relu, int gx) {
    __shared__ u16 As[128][32];
    __shared__ u16 Bs[128][32];
    const int tid = threadIdx.x;
    const int xcd = blockIdx.x & 7, j = blockIdx.x >> 3;
    const int m0 = (xcd * 16 + j / gx) * 128, n0 = (j % gx) * 128;
    const int lane = tid & 63, wid = tid >> 6;
    const int wm = (wid & 1) * 64, wn = (wid >> 1) * 64;
    const int m16 = lane & 15, quad = lane >> 4;
    f32x4 acc[4][4] = {};
    const int arow = tid >> 2;
    const int ac8  = (tid & 3) * 8;
    const u16* Ap0 = A  + (size_t)(m0 + arow) * K + ac8;
    const u16* Ap1 = A  + (size_t)(m0 + 64 + arow) * K + ac8;
    const u16* Bp0 = Bt + (size_t)(n0 + arow) * K + ac8;
    const u16* Bp1 = Bt + (size_t)(n0 + 64 + arow) * K + ac8;
    u16* lA0 = &As[arow][ac8];
    u16* lA1 = &As[64 + arow][ac8];
    u16* lB0 = &Bs[arow][ac8];
    u16* lB1 = &Bs[64 + arow][ac8];

    for (int k0 = 0; k0 < K; k0 += 32) {
        __syncthreads();
        gll16(Ap0 + k0, lA0);
        gll16(Ap1 + k0, lA1);
        gll16(Bp0 + k0, lB0);
        gll16(Bp1 + k0, lB1);
        __syncthreads();
        bf16x8 af[4], bfv[4];
#pragma unroll
        for (int i = 0; i < 4; ++i)
            af[i] = *(const bf16x8*)&As[wm + i * 16 + m16][quad * 8];
#pragma unroll
        for (int j2 = 0; j2 < 4; ++j2)
            bfv[j2] = *(const bf16x8*)&Bs[wn + j2 * 16 + m16][quad * 8];
#pragma unroll
        for (int i = 0; i < 4; ++i)
#pragma unroll
            for (int j2 = 0; j2 < 4; ++j2)
                acc[i][j2] = __builtin_amdgcn_mfma_f32_16x16x32_bf16(
                    af[i], bfv[j2], acc[i][j2], 0, 0, 0);
    }

#pragma unroll
    for (int i = 0; i < 4; ++i) {
        int row = m0 + wm + i * 16 + quad * 4;
#pragma unroll
        for (int j2 = 0; j2 < 4; ++j2) {
            int col = n0 + wn + j2 * 16 + m16;
            float bv = bf2f(bias[col]);
#pragma unroll
            for (int r = 0; r < 4; ++r) {
                float v = acc[i][j2][r] + bv;
                if (relu) v = fmaxf(v, 0.f);
                C[(size_t)(row + r) * N + col] = f2bf_fast(v);
            }
        }
    }
}

// ---------------- MFMA GEMM 64x128, BK=64 (QKV; vt epilogue) ---------------
__global__ __launch_bounds__(256) void k_gemm64(const u16* __restrict__ A,
                                                const u16* __restrict__ Bt,
                                                const u16* __restrict__ bias,
                                                u16* __restrict__ C,
                                                int N, int K, int relu,
                                                int gx, int mtpx,
                                                u16* __restrict__ vt) {
    __shared__ u16 As0[64][32], As1[64][32];
    __shared__ u16 Bs0[128][32], Bs1[128][32];
    const int tid = threadIdx.x;
    const int xcd = blockIdx.x & 7, j = blockIdx.x >> 3;
    const int m0 = (xcd * mtpx + j / gx) * 64, n0 = (j % gx) * 128;
    const int vmode = (vt != nullptr) && (n0 >= 512);
    const int lane = tid & 63, wid = tid >> 6;
    const int wm = (wid & 1) * 32, wn = (wid >> 1) * 64;
    const int m16 = lane & 15, quad = lane >> 4;
    f32x4 acc[2][4] = {};
    const int arow = tid >> 2;
    const int ac8  = (tid & 3) * 8;
    const u16* Ap  = A  + (size_t)(m0 + arow) * K + ac8;
    const u16* Bp0 = Bt + (size_t)(n0 + arow) * K + ac8;
    const u16* Bp1 = Bt + (size_t)(n0 + 64 + arow) * K + ac8;
    u16* lA0  = &As0[arow][ac8];
    u16* lA1  = &As1[arow][ac8];
    u16* lB00 = &Bs0[arow][ac8];
    u16* lB01 = &Bs0[64 + arow][ac8];
    u16* lB10 = &Bs1[arow][ac8];
    u16* lB11 = &Bs1[64 + arow][ac8];

    for (int k0 = 0; k0 < K; k0 += 64) {
        __syncthreads();
        gll16(Ap + k0,        lA0);
        gll16(Ap + k0 + 32,   lA1);
        gll16(Bp0 + k0,       lB00);
        gll16(Bp0 + k0 + 32,  lB10);
        gll16(Bp1 + k0,       lB01);
        gll16(Bp1 + k0 + 32,  lB11);
        __syncthreads();
#pragma unroll
        for (int ks = 0; ks < 2; ++ks) {
            bf16x8 af[2], bfv[4];
#pragma unroll
            for (int i = 0; i < 2; ++i)
                af[i] = ks == 0 ? *(const bf16x8*)&As0[wm + i * 16 + m16][quad * 8]
                                : *(const bf16x8*)&As1[wm + i * 16 + m16][quad * 8];
#pragma unroll
            for (int j2 = 0; j2 < 4; ++j2)
                bfv[j2] = ks == 0 ? *(const bf16x8*)&Bs0[wn + j2 * 16 + m16][quad * 8]
                                  : *(const bf16x8*)&Bs1[wn + j2 * 16 + m16][quad * 8];
#pragma unroll
            for (int i = 0; i < 2; ++i)
#pragma unroll
                for (int j2 = 0; j2 < 4; ++j2)
                    acc[i][j2] = __builtin_amdgcn_mfma_f32_16x16x32_bf16(
                        af[i], bfv[j2], acc[i][j2], 0, 0, 0);
        }
    }

#pragma unroll
    for (int i = 0; i < 2; ++i) {
        int row = m0 + wm + i * 16 + quad * 4;
#pragma unroll
        for (int j2 = 0; j2 < 4; ++j2) {
            int col = n0 + wn + j2 * 16 + m16;
            float bv = bf2f(bias[col]);
            if (vmode) {
                int ch = col - 512;
                u16x4 o;
#pragma unroll
                for (int r = 0; r < 4; ++r) o[r] = f2bf_fast(acc[i][j2][r] + bv);
                size_t vb = ((size_t)((row >> 10) * 4 + (ch >> 6)) * 64 + (ch & 63)) * 1024
                          + (row & 1023);
                *(u16x4*)&vt[vb] = o;
            } else {
#pragma unroll
                for (int r = 0; r < 4; ++r) {
                    float v = acc[i][j2][r] + bv;
                    if (relu) v = fmaxf(v, 0.f);
                    C[(size_t)(row + r) * N + col] = f2bf_fast(v);
                }
            }
        }
    }
}

// ---------------- MFMA GEMM 64x64, BK=64 — high-TLP for N=256 GEMMs --------
// gnx=4 -> 1024 blocks = 4 blocks/CU; LDS 16KB; ~50% occupancy.
__global__ __launch_bounds__(256) void k_gemm64n(const u16* __restrict__ A,
                                                 const u16* __restrict__ Bt,
                                                 const u16* __restrict__ bias,
                                                 u16* __restrict__ C,
                                                 int N, int K, int relu,
                                                 int gnx, int mtpx,
                                                 const float* __restrict__ gate) {
    __shared__ u16 As0[64][32], As1[64][32];
    __shared__ u16 Bs0[64][32], Bs1[64][32];
    const int tid = threadIdx.x;
    const int xcd = blockIdx.x & 7, j = blockIdx.x >> 3;
    const int m0 = (xcd * mtpx + j / gnx) * 64, n0 = (j % gnx) * 64;
    if (gate && gate[m0] == 0.f) return;
    const int lane = tid & 63, w = tid >> 6;
    const int m16 = lane & 15, quad = lane >> 4;
    f32x4 acc[4] = {};
    const int arow = tid >> 2;          // 0..63
    const int ac8  = (tid & 3) * 8;     // 0,8,16,24
    const u16* Ap = A  + (size_t)(m0 + arow) * K + ac8;
    const u16* Bp = Bt + (size_t)(n0 + arow) * K + ac8;
    u16* lA0 = &As0[arow][ac8];
    u16* lA1 = &As1[arow][ac8];
    u16* lB0 = &Bs0[arow][ac8];
    u16* lB1 = &Bs1[arow][ac8];

    for (int k0 = 0; k0 < K; k0 += 64) {
        __syncthreads();
        gll16(Ap + k0,       lA0);
        gll16(Ap + k0 + 32,  lA1);
        gll16(Bp + k0,       lB0);
        gll16(Bp + k0 + 32,  lB1);
        __syncthreads();
#pragma unroll
        for (int ks = 0; ks < 2; ++ks) {
            bf16x8 af = ks == 0 ? *(const bf16x8*)&As0[w * 16 + m16][quad * 8]
                                : *(const bf16x8*)&As1[w * 16 + m16][quad * 8];
#pragma unroll
            for (int nt = 0; nt < 4; ++nt) {
                bf16x8 bfv = ks == 0 ? *(const bf16x8*)&Bs0[nt * 16 + m16][quad * 8]
                                     : *(const bf16x8*)&Bs1[nt * 16 + m16][quad * 8];
                acc[nt] = __builtin_amdgcn_mfma_f32_16x16x32_bf16(af, bfv, acc[nt], 0, 0, 0);
            }
        }
    }

#pragma unroll
    for (int nt = 0; nt < 4; ++nt) {
        int col = n0 + nt * 16 + m16;
        float bv = bf2f(bias[col]);
        int row = m0 + w * 16 + quad * 4;
#pragma unroll
        for (int r = 0; r < 4; ++r) {
            float v = acc[nt][r] + bv;
            if (relu) v = fmaxf(v, 0.f);
            C[(size_t)(row + r) * N + col] = f2bf_fast(v);
        }
    }
}

// ---------------------------------------------------------------------------
// MFMA flash attention (structural floor): r13 structure + l-via-MFMA-ones.
// 256 thr / 4 waves / 64-key LDS tiles / XCD-swizzled 1024 blocks.
// ---------------------------------------------------------------------------
__global__ __launch_bounds__(256) void k_attn_mfma(const u16* __restrict__ QKV,
                                                   const u16* __restrict__ VT,
                                                   u16* __restrict__ CTX) {
    __shared__ u16 Ks[64][72];
    __shared__ u16 Vts[64][72];
    __shared__ u16 Ps[4][16][72];
    const int tid = threadIdx.x, lane = tid & 63, w = tid >> 6;
    const int quad = lane >> 4, c = lane & 15;
    const int blk = blockIdx.x;
    const int xcd = blk & 7, local = blk >> 3;
    const int bh = xcd * 8 + (local >> 4);
    const int qt = local & 15;
    const int b = bh >> 2, h = bh & 3;
    const int qrow0 = b * 1024 + qt * 64;

    const u16* qptr = QKV + (size_t)(qrow0 + w * 16 + c) * 768 + h * 64;
    bf16x8 aq0 = *(const bf16x8*)(qptr + quad * 8);
    bf16x8 aq1 = *(const bf16x8*)(qptr + 32 + quad * 8);

    bf16x8 ones;
    {
        union { u16 u; __bf16 h; } v; v.u = 0x3F80;
#pragma unroll
        for (int e = 0; e < 8; ++e) ones[e] = v.h;
    }

    f32x4 acc_o[4] = {};
    f32x4 acc_l = {};

    const u16* kbase  = QKV + (size_t)(b * 1024) * 768 + 256 + h * 64;
    const u16* vtbase = VT + (size_t)(bh * 64) * 1024;
    const int skk = tid >> 3, sc8 = (tid & 7) * 8;

    for (int t = 0; t < 16; ++t) {
        __syncthreads();
#pragma unroll
        for (int it = 0; it < 2; ++it) {
            int rr = skk + 32 * it;
            *(u16x8*)&Ks[rr][sc8]  = *(const u16x8*)(kbase + (size_t)(t * 64 + rr) * 768 + sc8);
            *(u16x8*)&Vts[rr][sc8] = *(const u16x8*)(vtbase + (size_t)rr * 1024 + t * 64 + sc8);
        }
        __syncthreads();

        f32x4 s[4];
#pragma unroll
        for (int nt = 0; nt < 4; ++nt) {
            f32x4 z = {};
            bf16x8 bk0 = *(const bf16x8*)&Ks[nt * 16 + c][quad * 8];
            bf16x8 bk1 = *(const bf16x8*)&Ks[nt * 16 + c][32 + quad * 8];
            z = __builtin_amdgcn_mfma_f32_16x16x32_bf16(aq0, bk0, z, 0, 0, 0);
            s[nt] = __builtin_amdgcn_mfma_f32_16x16x32_bf16(aq1, bk1, z, 0, 0, 0);
        }

#pragma unroll
        for (int nt = 0; nt < 4; ++nt)
#pragma unroll
            for (int r = 0; r < 4; ++r)
                Ps[w][quad * 4 + r][nt * 16 + c] = f2bf_fast(exp2f(fminf(s[nt][r], 80.f)));

#pragma unroll
        for (int ks = 0; ks < 2; ++ks) {
            bf16x8 ap = *(const bf16x8*)&Ps[w][c][ks * 32 + quad * 8];
            acc_l = __builtin_amdgcn_mfma_f32_16x16x32_bf16(ap, ones, acc_l, 0, 0, 0);
#pragma unroll
            for (int nt = 0; nt < 4; ++nt) {
                bf16x8 bv = *(const bf16x8*)&Vts[nt * 16 + c][ks * 32 + quad * 8];
                acc_o[nt] = __builtin_amdgcn_mfma_f32_16x16x32_bf16(ap, bv, acc_o[nt], 0, 0, 0);
            }
        }
    }

#pragma unroll
    for (int nt = 0; nt < 4; ++nt) {
        int col = h * 64 + nt * 16 + c;
#pragma unroll
        for (int r = 0; r < 4; ++r) {
            int row = qrow0 + w * 16 + quad * 4 + r;
            CTX[(size_t)row * 256 + col] = f2bf_fast(acc_o[nt][r] / acc_l[r]);
        }
    }
}

// ---------------- LayerNorm (wave per row) — LN1 only ----------------
__global__ __launch_bounds__(256) void k_ln(const u16* __restrict__ A,
                                            const u16* __restrict__ R,
                                            const u16* __restrict__ g,
                                            const u16* __restrict__ be,
                                            u16* __restrict__ out) {
    int w = threadIdx.x >> 6, lane = threadIdx.x & 63;
    int row = blockIdx.x * 4 + w;
    size_t base = (size_t)row * 256 + lane * 4;
    u16x4 a4 = *(const u16x4*)&A[base];
    u16x4 r4 = *(const u16x4*)&R[base];
    float v[4];
    float s = 0.f, sq = 0.f;
#pragma unroll
    for (int j = 0; j < 4; ++j) {
        v[j] = bf2f(a4[j]) + bf2f(r4[j]);
        s += v[j]; sq += v[j] * v[j];
    }
    for (int off = 32; off >= 1; off >>= 1) { s += __shfl_xor(s, off); sq += __shfl_xor(sq, off); }
    float mean = s * (1.f / 256.f);
    float var  = sq * (1.f / 256.f) - mean * mean;
    float rs   = rsqrtf(var + 1e-5f);
    u16x4 o;
#pragma unroll
    for (int j = 0; j < 4; ++j) {
        int d = lane * 4 + j;
        o[j] = f2bf((v[j] - mean) * rs * bf2f(g[d]) + bf2f(be[d]));
    }
    *(u16x4*)&out[base] = o;
}

// ---------------- LN2 + logits / KL / flags fused (KL partials) ------------
__global__ __launch_bounds__(256) void k_logits(const u16* __restrict__ FFO,
                                                const u16* __restrict__ Y1,
                                                const u16* __restrict__ g2,
                                                const u16* __restrict__ be2,
                                                const u16* __restrict__ Wl,
                                                const u16* __restrict__ bl,
                                                u16* __restrict__ Y2,
                                                float* __restrict__ klpart,
                                                int* __restrict__ flags) {
    const int tid = threadIdx.x, lane = tid & 63, w = tid >> 6;
    float wv[4][3], gv[4], bev[4];
#pragma unroll
    for (int j = 0; j < 4; ++j) {
        int d = lane * 4 + j;
        gv[j]  = bf2f(g2[d]);
        bev[j] = bf2f(be2[d]);
#pragma unroll
        for (int c = 0; c < 3; ++c) wv[j][c] = bf2f(Wl[d * 3 + c]);
    }
    const float b0 = bf2f(bl[0]), b1 = bf2f(bl[1]), b2 = bf2f(bl[2]);
    float klsum = 0.f;
    const int row0 = blockIdx.x * 16 + w * 4;
    for (int i = 0; i < 4; ++i) {
        int row = row0 + i;
        size_t base = (size_t)row * 256 + lane * 4;
        u16x4 f4 = *(const u16x4*)&FFO[base];
        u16x4 y4 = *(const u16x4*)&Y1[base];
        float v[4];
        float s = 0.f, sq = 0.f;
#pragma unroll
        for (int j = 0; j < 4; ++j) {
            v[j] = bf2f(f4[j]) + bf2f(y4[j]);
            s += v[j]; sq += v[j] * v[j];
        }
        for (int off = 32; off >= 1; off >>= 1) { s += __shfl_xor(s, off); sq += __shfl_xor(sq, off); }
        float mean = s * (1.f / 256.f);
        float var  = sq * (1.f / 256.f) - mean * mean;
        float rs   = rsqrtf(var + 1e-5f);
        u16x4 o;
        float a0 = 0.f, a1 = 0.f, a2 = 0.f;
#pragma unroll
        for (int j = 0; j < 4; ++j) {
            float yn = (v[j] - mean) * rs * gv[j] + bev[j];
            o[j] = f2bf(yn);
            float y = bf2f(o[j]);
            a0 += y * wv[j][0]; a1 += y * wv[j][1]; a2 += y * wv[j][2];
        }
        *(u16x4*)&Y2[base] = o;
        for (int off = 32; off >= 1; off >>= 1) {
            a0 += __shfl_xor(a0, off); a1 += __shfl_xor(a1, off); a2 += __shfl_xor(a2, off);
        }
        if (lane == 0) {
            float l0 = a0 + b0, l1 = a1 + b1, l2 = a2 + b2;
            float mx = fmaxf(l0, fmaxf(l1, l2));
            float lse = mx + __logf(__expf(l0 - mx) + __expf(l1 - mx) + __expf(l2 - mx));
            klsum += lse - (l0 + l1 + l2) * (1.f / 3.f) - 1.0986122886681098f;
            int am = 0; float bv = l0;
            if (l1 > bv) { bv = l1; am = 1; }
            if (l2 > bv) { am = 2; }
            int l = row & 1023;
            flags[row] = (am == 0 && l != 0) ? 1 : 0;
        }
    }
    __shared__ float kls[4];
    if (lane == 0) kls[w] = klsum;
    __syncthreads();
    if (tid == 0) klpart[blockIdx.x] = kls[0] + kls[1] + kls[2] + kls[3];
}

// per-batch exclusive scan: wave shuffle-scan, 2 barriers
__global__ void k_scan(const int* __restrict__ flags, int* __restrict__ seg) {
    __shared__ int wsum[16];
    int b = blockIdx.x, t = threadIdx.x;
    int lane = t & 63, w = t >> 6;
    int f = flags[b * 1024 + t];
    int x = f;
#pragma unroll
    for (int off = 1; off < 64; off <<= 1) {
        int v = __shfl_up(x, off);
        if (lane >= off) x += v;
    }
    if (lane == 63) wsum[w] = x;
    __syncthreads();
    if (w == 0) {
        int s = (lane < 16) ? wsum[lane] : 0;
#pragma unroll
        for (int off = 1; off < 16; off <<= 1) {
            int v = __shfl_up(s, off);
            if (lane >= off) s += v;
        }
        if (lane < 16) wsum[lane] = s;
    }
    __syncthreads();
    int prefix = (w > 0) ? wsum[w - 1] : 0;
    seg[b * 1024 + t] = prefix + x - f;
}

// ---------------- segmean: one block per (b,s); binary-search the run ------
__global__ __launch_bounds__(64) void k_segmean(const u16* __restrict__ Y,
                                                const int* __restrict__ seg,
                                                u16* __restrict__ means,
                                                float* __restrict__ cnt) {
    int g = blockIdx.x, lane = threadIdx.x;
    int b = g >> 10, s = g & 1023;
    const int* sb = seg + b * 1024;
    int target = s + (lane & 1);
    int lo = 0, hi = 1024;
    while (lo < hi) {
        int mid = (lo + hi) >> 1;
        if (sb[mid] < target) lo = mid + 1; else hi = mid;
    }
    int start = __shfl(lo, 0);
    int end   = __shfl(lo, 1);
    int n = end - start;
    if (lane == 0) cnt[g] = (float)n;
    if (n <= 0) return;
    f32x4 acc = {};
    for (int row = start; row < end; ++row) {
        u16x4 y4 = *(const u16x4*)&Y[(size_t)(b * 1024 + row) * 256 + lane * 4];
        acc[0] += bf2f(y4[0]); acc[1] += bf2f(y4[1]);
        acc[2] += bf2f(y4[2]); acc[3] += bf2f(y4[3]);
    }
    float inv = 1.f / (float)n;
    u16x4 o;
#pragma unroll
    for (int j = 0; j < 4; ++j) o[j] = f2bf(acc[j] * inv);
    *(u16x4*)&means[(size_t)g * 256 + lane * 4] = o;
}

// ---------------- predicate head: plain per-block partials ----------------
__global__ __launch_bounds__(256) void k_preds(const u16* __restrict__ T,
                                               const u16* __restrict__ Wp2,
                                               const u16* __restrict__ bp2,
                                               const u16* __restrict__ wc,
                                               const u16* __restrict__ bc,
                                               const float* __restrict__ cnt,
                                               float* __restrict__ predp) {
    const int tid = threadIdx.x, lane = tid & 63, w = tid >> 6;
    float lwp[4];
#pragma unroll
    for (int j = 0; j < 4; ++j) lwp[j] = bf2f(Wp2[lane * 4 + j]);
    const float fb = bf2f(bp2[0]), fw = bf2f(wc[0]), fc = bf2f(bc[0]);
    float csum = 0.f, vsum = 0.f;
    const int g0 = blockIdx.x * 16 + w * 4;
    if (cnt[g0] != 0.f) {
        for (int i = 0; i < 4; ++i) {
            int g = g0 + i;
            u16x4 t4 = *(const u16x4*)&T[(size_t)g * 256 + lane * 4];
            float a = 0.f;
#pragma unroll
            for (int j = 0; j < 4; ++j) a += bf2f(t4[j]) * lwp[j];
            for (int off = 32; off >= 1; off >>= 1) a += __shfl_xor(a, off);
            if (lane == 0 && cnt[g] > 0.f) {
                float pred = 1.f / (1.f + __expf(-(a + fb)));
                csum += pred * fw + fc;
                vsum += 1.f;
            }
        }
    }
    __shared__ float cs[4], vs[4];
    if (lane == 0) { cs[w] = csum; vs[w] = vsum; }
    __syncthreads();
    if (tid == 0) {
        predp[2 * blockIdx.x]     = cs[0] + cs[1] + cs[2] + cs[3];
        predp[2 * blockIdx.x + 1] = vs[0] + vs[1] + vs[2] + vs[3];
    }
}

// ---------------- finalize: sum KL + pred partials, store ----------------
__global__ void k_final(const float* __restrict__ predp, const float* __restrict__ klp,
                        const int* __restrict__ detp, void* __restrict__ outv) {
    int t = threadIdx.x;   // 64
    float k = 0.f;
    for (int i = t; i < 1024; i += 64) k += klp[i];
    for (int off = 32; off >= 1; off >>= 1) k += __shfl_xor(k, off);
    float ktot = __shfl(k, 0);
    int batch = t >> 2, ch = t & 3;
    float c = 0.f, v = 0.f;
    for (int i = 0; i < 16; ++i) {
        int blk = batch * 64 + ch * 16 + i;
        c += predp[2 * blk];
        v += predp[2 * blk + 1];
    }
    c += __shfl_xor(c, 1); c += __shfl_xor(c, 2);
    v += __shfl_xor(v, 1); v += __shfl_xor(v, 2);
    int mode = get_mode(detp);
    if ((t & 3) == 0) {
        float d = v, nm = c;
        if (!(d > 0.f)) d = 1.f;
        if (isnan(nm) || isinf(nm)) nm = 0.f;
        float val = 1.f / (1.f + __expf(-nm / d));
        if (mode) ((float*)outv)[batch] = val;
        else      ((u16*)outv)[batch]   = f2bf(val);
    }
    if (t == 1) {
        float val = ktot * (1.f / 16.f);
        if (isnan(val) || isinf(val)) val = 0.f;
        if (mode) ((float*)outv)[16] = val;
        else      ((u16*)outv)[16]   = f2bf(val);
    }
}

// ---------------------------------------------------------------------------
extern "C" void kernel_launch(void* const* d_in, const int* in_sizes, int n_in,
                              void* d_out, int out_size, void* d_ws, size_t ws_size,
                              hipStream_t stream) {
    const int* shape_idxs = (const int*)d_in[0];
    const int* color_idxs = (const int*)d_in[1];
    char* ws = (char*)d_ws;
    const size_t MB = 1024 * 1024;

    if (ws_size < 90 * MB) {
        int wsMB = (int)(ws_size >> 20); if (wsMB > 250) wsMB = 250;
        k_sentinel_f32<<<1, 32, 0, stream>>>((float*)d_out, 200 + wsMB);
        return;
    }

    // ---- arena ----
    u16*   X     = (u16*)(ws);
    u16*   QKVb  = (u16*)(ws + 8 * MB);
    u16*   VT    = (u16*)(ws + 32 * MB);
    u16*   CTX   = (u16*)(ws + 40 * MB);
    u16*   CTXP  = (u16*)(ws + 48 * MB);
    u16*   Y1    = (u16*)(ws + 64 * MB);
    u16*   Hb    = (u16*)(ws);
    u16*   FFO   = (u16*)(ws + 72 * MB);
    u16*   Y2    = (u16*)(ws);
    u16*   MEANS = (u16*)(ws + 24 * MB);
    u16*   TB    = (u16*)(ws + 32 * MB);
    int*   FLAGS = (int*)(ws + 80 * MB);
    int*   SEG   = (int*)(ws + 80 * MB + 65536);
    float* CNT   = (float*)(ws + 80 * MB + 131072);
    float* KLP   = (float*)(ws + 80 * MB + 262144);
    float* PREDP = (float*)(ws + 80 * MB + 327680);
    u16*   W3T   = (u16*)(ws + 81 * MB);
    u16*   WoT   = (u16*)(ws + 81 * MB + 786432);
    u16*   Wp1T  = (u16*)(ws + 81 * MB + 917504);
    u16*   W1T   = (u16*)(ws + 82 * MB);
    u16*   W2T   = (u16*)(ws + 83 * MB);
    int*   DETP  = (int*)(ws + 84 * MB);
    u16*   ING   = (u16*)(ws + 85 * MB);

    const float QSCALE = 0.125f * 1.44269504f;

    // prep table: 7 transposes + 17 small-tensor ingests
    PrepTab tt;
    const void* tsrc[7] = {d_in[4], d_in[6], d_in[8], d_in[10], d_in[22], d_in[14], d_in[16]};
    u16* tdst[7] = {W3T, W3T + 256 * 256, W3T + 512 * 256, WoT, Wp1T, W1T, W2T};
    int tK[7] = {256, 256, 256, 256, 256, 256, 2048};
    int tN[7] = {256, 256, 256, 256, 256, 2048, 256};
    int ts = 0;
    for (int i = 0; i < 7; ++i) {
        tt.src[i] = tsrc[i]; tt.dst[i] = tdst[i]; tt.K[i] = tK[i]; tt.N[i] = tN[i];
        tt.scale[i] = (i == 0) ? QSCALE : 1.0f;
        tt.tstart[i] = ts;
        ts += (tK[i] >> 5) * (tN[i] >> 5);
    }
    tt.tstart[7] = ts;

    static const int II[17]  = {5, 7, 9, 11, 12, 13, 15, 17, 18, 19, 20, 21, 23, 24, 25, 26, 27};
    static const int IN[17]  = {256, 256, 256, 256, 256, 256, 2048, 256, 256, 256, 768, 3, 256, 256, 1, 1, 1};
    unsigned off = 0;
    for (int i = 0; i < 17; ++i) {
        tt.isrc[i] = d_in[II[i]];
        tt.in[i] = IN[i];
        tt.iscale[i] = 1.0f;
        if (i == 0) { tt.idstoff[0] = off; off += 768; }
        else if (i == 1) tt.idstoff[1] = tt.idstoff[0] + 256;
        else if (i == 2) tt.idstoff[2] = tt.idstoff[0] + 512;
        else { tt.idstoff[i] = off; off += (unsigned)((IN[i] + 8) & ~7); }
    }
    tt.iscale[0] = QSCALE;   // bq
    tt.ing = ING;
    const u16* ib3  = ING + tt.idstoff[0];
    const u16* ibo  = ING + tt.idstoff[3];
    const u16* ig1  = ING + tt.idstoff[4];  const u16* ibe1 = ING + tt.idstoff[5];
    const u16* ibf1 = ING + tt.idstoff[6];  const u16* ibf2 = ING + tt.idstoff[7];
    const u16* ig2  = ING + tt.idstoff[8];  const u16* ibe2 = ING + tt.idstoff[9];
    const u16* iWl  = ING + tt.idstoff[10]; const u16* ibl  = ING + tt.idstoff[11];
    const u16* ibp1 = ING + tt.idstoff[12]; const u16* iWp2 = ING + tt.idstoff[13];
    const u16* ibp2 = ING + tt.idstoff[14]; const u16* iwc  = ING + tt.idstoff[15];
    const u16* ibc  = ING + tt.idstoff[16];

    // 0) detect (plain partials)
    k_detect<<<64, 256, 0, stream>>>((const u16*)d_in[14], DETP);
    // 1) prep: transposes + small ingest, one launch
    k_prep<<<ts + 17, 256, 0, stream>>>(tt, DETP);
    // 2) embedding
    k_embed<<<2048, 256, 0, stream>>>(shape_idxs, color_idxs, d_in[2], d_in[3], X, DETP);
    // 3) fused QKV projection; V columns written directly in VT layout
    k_gemm64<<<1536, 256, 0, stream>>>(X, W3T, ib3, QKVb, 768, 256, 0, 6, 32, VT);
    // 4) attention
    k_attn_mfma<<<1024, 256, 0, stream>>>(QKVb, VT, CTX);
    // 5) Wo (64x64 high-TLP) + LN1
    k_gemm64n<<<1024, 256, 0, stream>>>(CTX, WoT, ibo, CTXP, 256, 256, 0, 4, 32, nullptr);
    k_ln<<<4096, 256, 0, stream>>>(CTXP, X, ig1, ibe1, Y1);
    // 6) FFN: FFN1 128-tile, FFN2 64x64 high-TLP
    k_gemm_bt<<<16 * 128, 256, 0, stream>>>(Y1, W1T, ibf1, Hb, 2048, 256, 1, 16);
    k_gemm64n<<<1024, 256, 0, stream>>>(Hb, W2T, ibf2, FFO, 256, 2048, 0, 4, 32, nullptr);
    // 7) LN2 + logits / KL / flags (fused; writes Y2, KL partials)
    k_logits<<<1024, 256, 0, stream>>>(FFO, Y1, ig2, ibe2, iWl, ibl, Y2, KLP, FLAGS);
    // 8) per-batch exclusive scan
    k_scan<<<16, 1024, 0, stream>>>(FLAGS, SEG);
    // 9) segment means
    k_segmean<<<16384, 64, 0, stream>>>(Y2, SEG, MEANS, CNT);
    // 10) predicate net (gated, 64x64 high-TLP) -> plain partials
    k_gemm64n<<<1024, 256, 0, stream>>>(MEANS, Wp1T, ibp1, TB, 256, 256, 1, 4, 32, CNT);
    k_preds<<<1024, 256, 0, stream>>>(TB, iWp2, ibp2, iwc, ibc, CNT, PREDP);
    // 11) finalize + store
    k_final<<<1, 64, 0, stream>>>(PREDP, KLP, DETP, d_out);
}